// Round 4
// baseline (1788.173 us; speedup 1.0000x reference)
//
#include <hip/hip_runtime.h>
#include <math.h>

// ===========================================================================
// AlexCapsNet forward. Big convs + FC2 via fp16x3-split MFMA (16x16x32_f16).
// a = ah + al/2048 (al stored pre-scaled by 2048 to stay in f16 normal range).
// C = sum ah*bh  +  (sum ah*bl + al*bh) / 2048      (al*bl dropped, ~2^-22)
//
// Round 10: counted-vmcnt software pipeline (T3+T4+T5).
//  r9 rocprof: conv4 MfmaUtil 36.5% = the m97-structure ceiling (full vmcnt
//  drain at every K-step barrier). New structure per K-step:
//    STAGE(next buf)                      // 8 gload_lds per wave, in flight
//    s_waitcnt vmcnt(8)                   // waits ONLY current tile's loads
//    raw s_barrier + sched_barrier(0)     // no compiler vmcnt(0) drain
//    MFMA cluster (setprio 1/0)
//    raw s_barrier
//  Double-buffered LDS (128 KiB), 512 threads / 8 waves (2/SIMD), per-wave
//  64x32 output. Per-wave DMA count uniform -> vmcnt immediate exact
//  (8 for NT=128 & fc2, 6 for NT=64 caps). Same swizzle + numerics as r9.
// ===========================================================================

#define BATCH 512

typedef _Float16 half8  __attribute__((ext_vector_type(8)));
typedef _Float16 half4v __attribute__((ext_vector_type(4)));
typedef float   float4v __attribute__((ext_vector_type(4)));

// ---------------- global->LDS 16B DMA helper -------------------------------
__device__ __forceinline__ void gload_lds16(const void* g, void* l)
{
    __builtin_amdgcn_global_load_lds(
        (const __attribute__((address_space(1))) unsigned int*)g,
        (__attribute__((address_space(3))) unsigned int*)l,
        16, 0, 0);
}

template<int N> __device__ __forceinline__ void waitcnt_vm()
{
    static_assert(N == 0 || N == 6 || N == 8, "unsupported vmcnt");
    if constexpr (N == 8)      asm volatile("s_waitcnt vmcnt(8)" ::: "memory");
    else if constexpr (N == 6) asm volatile("s_waitcnt vmcnt(6)" ::: "memory");
    else                       asm volatile("s_waitcnt vmcnt(0)" ::: "memory");
}

// ---------------- zero page ------------------------------------------------
__global__ __launch_bounds__(64) void zero_kernel(float* __restrict__ z)
{
    z[threadIdx.x] = 0.f;
}

// ---------------- fp32 -> (hi f16, lo f16*2048) split (linear) -------------
__global__ __launch_bounds__(256) void split_kernel(
    const float* __restrict__ src, _Float16* __restrict__ hi,
    _Float16* __restrict__ lo, int n)
{
    int idx = blockIdx.x * 256 + threadIdx.x;
    if (idx >= n) return;
    float v = src[idx];
    _Float16 h = (_Float16)v;
    hi[idx] = h;
    lo[idx] = (_Float16)((v - (float)h) * 2048.0f);
}

// -------- weight reorder [oc][ic][kh][kw] -> [oc][(kh,kw,ic) padded] + split
__global__ __launch_bounds__(256) void wsplit_pad_kernel(
    const float* __restrict__ src, _Float16* __restrict__ hi,
    _Float16* __restrict__ lo, int IC, int KK, int K, int KP, int total)
{
    int idx = blockIdx.x * 256 + threadIdx.x;   // idx = oc*KP + k
    if (idx >= total) return;
    int k  = idx % KP;
    int oc = idx / KP;
    float v = 0.f;
    if (k < K) {
        int khkw = k / IC;
        int ic   = k - khkw * IC;
        v = src[((size_t)(oc * IC + ic)) * KK + khkw];
    }
    _Float16 h = (_Float16)v;
    hi[idx] = h;
    lo[idx] = (_Float16)((v - (float)h) * 2048.0f);
}

// ---------------- conv1(1->96,3x3,p1) + relu + maxpool(3,2,1) fused --------
__global__ __launch_bounds__(256) void conv1_pool_nhwc(
    const float* __restrict__ x, const float* __restrict__ w1,
    const float* __restrict__ b1, _Float16* __restrict__ oh_,
    _Float16* __restrict__ ol_)
{
    int idx = blockIdx.x * 256 + threadIdx.x;   // = ((n*14+oh)*14+ow)*96+oc
    if (idx >= 512 * 14 * 14 * 96) return;
    int oc = idx % 96; int t1 = idx / 96;
    int ow = t1 % 14;  int t2 = t1 / 14;
    int oh = t2 % 14;  int n  = t2 / 14;
    const float* xi = x + n * 784;
    float w[9];
#pragma unroll
    for (int i = 0; i < 9; ++i) w[i] = w1[oc * 9 + i];
    float bias = b1[oc];
    float best = -3.4e38f;
#pragma unroll
    for (int dy = 0; dy < 3; ++dy) {
        int ph = oh * 2 - 1 + dy;
        if ((unsigned)ph >= 28u) continue;
#pragma unroll
        for (int dx = 0; dx < 3; ++dx) {
            int pw = ow * 2 - 1 + dx;
            if ((unsigned)pw >= 28u) continue;
            float s = bias;
#pragma unroll
            for (int ky = 0; ky < 3; ++ky) {
                int iy = ph - 1 + ky;
                if ((unsigned)iy >= 28u) continue;
#pragma unroll
                for (int kx = 0; kx < 3; ++kx) {
                    int ix = pw - 1 + kx;
                    if ((unsigned)ix >= 28u) continue;
                    s = fmaf(w[ky * 3 + kx], xi[iy * 28 + ix], s);
                }
            }
            s = fmaxf(s, 0.f);
            best = fmaxf(best, s);
        }
    }
    _Float16 h = (_Float16)best;
    oh_[idx] = h;
    ol_[idx] = (_Float16)((best - (float)h) * 2048.0f);
}

// ---------------- NHWC maxpool (fp32 in) -> split f16 hi/lo out ------------
template<int NB, int C, int H, int W, int OH, int OW, int KS, int STR, int PADP>
__global__ __launch_bounds__(256) void maxpool_nhwc_split(
    const float* __restrict__ in, _Float16* __restrict__ po,
    _Float16* __restrict__ pl)
{
    constexpr int TOTAL = NB * OH * OW * C;
    int idx = blockIdx.x * 256 + threadIdx.x;   // = ((n*OH+oh)*OW+ow)*C+c
    if (idx >= TOTAL) return;
    int c  = idx % C;  int t1 = idx / C;
    int ow = t1 % OW;  int t2 = t1 / OW;
    int oh = t2 % OH;  int n  = t2 / OH;
    const float* ip = in + (size_t)n * (H * W * C) + c;
    float best = -3.4e38f;
#pragma unroll
    for (int dy = 0; dy < KS; ++dy) {
        int ih = oh * STR - PADP + dy;
        if ((unsigned)ih >= (unsigned)H) continue;
#pragma unroll
        for (int dx = 0; dx < KS; ++dx) {
            int iw = ow * STR - PADP + dx;
            if ((unsigned)iw >= (unsigned)W) continue;
            best = fmaxf(best, ip[(size_t)(ih * W + iw) * C]);
        }
    }
    _Float16 h = (_Float16)best;
    po[idx] = h;
    pl[idx] = (_Float16)((best - (float)h) * 2048.0f);
}

// ---------------- fp16x3 MFMA conv, counted-vmcnt pipeline -----------------
// M = OC (tile 128), N = batch*OHW (tile NT), K = KH*KH*IC (step 64).
// 512 threads / 8 waves, per-wave output 64 x NT/4. Double-buffered LDS.
// LDS rows = 64 halfs, phys_slot = slot ^ (row&7); DMA source pre-inverse-
// swizzled per lane (both-sides rule). OOB taps DMA from zero page.
// OUTMODE: 0 = fp32 NHWC + relu, 1 = split f16 NHWC + relu, 2 = fp32 NCHW.
template<int IC, int H, int W, int KH, int PAD, int OC, int NT, int OUTMODE>
__global__ __launch_bounds__(512, 2) void conv_pipe(
    const _Float16* __restrict__ inh, const _Float16* __restrict__ inl,
    const _Float16* __restrict__ whi, const _Float16* __restrict__ wlo,
    const float* __restrict__ bias, const float* __restrict__ zpage,
    float* __restrict__ outf, _Float16* __restrict__ outh,
    _Float16* __restrict__ outl, int n_base)
{
    constexpr int OH  = H + 2 * PAD - KH + 1;
    constexpr int OW  = W + 2 * PAD - KH + 1;
    constexpr int OHW = OH * OW;
    constexpr int K   = IC * KH * KH;
    constexpr int KP  = (K + 63) & ~63;
    constexpr int NFRAG = NT / 64;            // per-wave N fragments (2 or 1)
    constexpr int NBI   = NT / 64;            // B DMA instrs per wave per comp
    constexpr int VMC   = 4 + 2 * NBI;        // per-wave loads per stage
    constexpr bool UNIF = (IC % 64 == 0) && (KP == K);
    constexpr int HWIC = H * W * IC;

    const int t    = threadIdx.x;
    const int lane = t & 63;
    const int wid  = t >> 6;                  // 0..7
    const int l15  = lane & 15;
    const int quad = lane >> 4;
    const int wm   = (wid >> 2) << 6;         // 0 / 64
    const int wn   = (wid & 3) * (NT / 4);

    const int drow  = lane >> 3;
    const int pslot = lane & 7;
    const int slog  = pslot ^ drow;

    __shared__ __align__(16) _Float16 AhS[2][128 * 64];
    __shared__ __align__(16) _Float16 AlS[2][128 * 64];
    __shared__ __align__(16) _Float16 BhS[2][NT * 64];
    __shared__ __align__(16) _Float16 BlS[2][NT * 64];

    const int n0 = blockIdx.x * NT;
    const int m0 = blockIdx.y << 7;

    float4v acc1[4 * NFRAG], acc2[4 * NFRAG];
#pragma unroll
    for (int i = 0; i < 4 * NFRAG; ++i) {
        acc1[i] = (float4v)(0.f);
        acc2[i] = (float4v)(0.f);
    }

    // per-lane B geometry (per DMA instr)
    int bU[NBI], ohU[NBI], owU[NBI];
#pragma unroll
    for (int ii = 0; ii < NBI; ++ii) {
        int nl = ((wid * NBI + ii) << 3) + drow;
        int gn = n_base + n0 + nl;
        int b  = gn / OHW;
        int p  = gn - b * OHW;
        int o  = p / OW;
        bU[ii] = b; ohU[ii] = o; owU[ii] = p - o * OW;
    }

    auto STAGE = [&](int buf, int kb_s) {
#pragma unroll
        for (int ii = 0; ii < 2; ++ii) {
            const int iA = (wid << 1) + ii;
            const size_t go = (size_t)(m0 + (iA << 3) + drow) * KP + kb_s + (slog << 3);
            gload_lds16(whi + go, &AhS[buf][iA << 9]);
            gload_lds16(wlo + go, &AlS[buf][iA << 9]);
        }
        if constexpr (UNIF) {
            const int khkw = kb_s / IC;
            const int icb  = kb_s - khkw * IC;
            const int kh = khkw / KH;
            const int kw = khkw - kh * KH;
#pragma unroll
            for (int ii = 0; ii < NBI; ++ii) {
                const int iB = wid * NBI + ii;
                const int ih = ohU[ii] + kh - PAD;
                const int iw = owU[ii] + kw - PAD;
                const bool ok = ((unsigned)ih < (unsigned)H) && ((unsigned)iw < (unsigned)W);
                const size_t off = (size_t)bU[ii] * HWIC + (ih * W + iw) * IC + icb + (slog << 3);
                gload_lds16(ok ? inh + off : (const _Float16*)zpage, &BhS[buf][iB << 9]);
                gload_lds16(ok ? inl + off : (const _Float16*)zpage, &BlS[buf][iB << 9]);
            }
        } else {
            const int kpl = kb_s + (slog << 3);      // per-lane k (8-aligned; IC%8==0)
            const int kkl = kpl / IC;
            const int icl = kpl - kkl * IC;
            const int khl = kkl / KH;
            const int kwl = kkl - khl * KH;
#pragma unroll
            for (int ii = 0; ii < NBI; ++ii) {
                const int iB = wid * NBI + ii;
                const int ih = ohU[ii] + khl - PAD;
                const int iw = owU[ii] + kwl - PAD;
                const bool ok = (kpl < K) && ((unsigned)ih < (unsigned)H) &&
                                ((unsigned)iw < (unsigned)W);
                const size_t off = (size_t)bU[ii] * HWIC + (ih * W + iw) * IC + icl;
                gload_lds16(ok ? inh + off : (const _Float16*)zpage, &BhS[buf][iB << 9]);
                gload_lds16(ok ? inl + off : (const _Float16*)zpage, &BlS[buf][iB << 9]);
            }
        }
    };

    auto COMPUTE = [&](int buf) {
        const _Float16* Ahb = &AhS[buf][0];
        const _Float16* Alb = &AlS[buf][0];
        const _Float16* Bhb = &BhS[buf][0];
        const _Float16* Blb = &BlS[buf][0];
#pragma unroll
        for (int kh2 = 0; kh2 < 2; ++kh2) {
            half8 a_h[4], a_l[4], b_h[NFRAG], b_l[NFRAG];
#pragma unroll
            for (int i = 0; i < 4; ++i) {
                const int r  = wm + (i << 4) + l15;
                const int sl = ((kh2 << 2) + quad) ^ (r & 7);
                const int off = (r << 6) + (sl << 3);
                a_h[i] = *(const half8*)&Ahb[off];
                a_l[i] = *(const half8*)&Alb[off];
            }
#pragma unroll
            for (int i = 0; i < NFRAG; ++i) {
                const int r  = wn + (i << 4) + l15;
                const int sl = ((kh2 << 2) + quad) ^ (r & 7);
                const int off = (r << 6) + (sl << 3);
                b_h[i] = *(const half8*)&Bhb[off];
                b_l[i] = *(const half8*)&Blb[off];
            }
            __builtin_amdgcn_s_setprio(1);
#pragma unroll
            for (int mi = 0; mi < 4; ++mi)
#pragma unroll
                for (int ni = 0; ni < NFRAG; ++ni) {
                    const int ix = mi * NFRAG + ni;
                    acc1[ix] = __builtin_amdgcn_mfma_f32_16x16x32_f16(a_h[mi], b_h[ni], acc1[ix], 0, 0, 0);
                    acc2[ix] = __builtin_amdgcn_mfma_f32_16x16x32_f16(a_h[mi], b_l[ni], acc2[ix], 0, 0, 0);
                    acc2[ix] = __builtin_amdgcn_mfma_f32_16x16x32_f16(a_l[mi], b_h[ni], acc2[ix], 0, 0, 0);
                }
            __builtin_amdgcn_s_setprio(0);
        }
    };

    // ---- pipelined main loop ----
    STAGE(0, 0);
    int cur = 0;
#pragma unroll 1
    for (int kb = 0; kb + 64 < KP; kb += 64) {
        STAGE(cur ^ 1, kb + 64);
        waitcnt_vm<VMC>();
        __builtin_amdgcn_s_barrier();
        __builtin_amdgcn_sched_barrier(0);
        COMPUTE(cur);
        __builtin_amdgcn_sched_barrier(0);
        __builtin_amdgcn_s_barrier();
        cur ^= 1;
    }
    waitcnt_vm<0>();
    __builtin_amdgcn_s_barrier();
    __builtin_amdgcn_sched_barrier(0);
    COMPUTE(cur);

    // ---- epilogue: combine, bias(+relu), NHWC stores ----
#pragma unroll
    for (int mi = 0; mi < 4; ++mi)
#pragma unroll
        for (int ni = 0; ni < NFRAG; ++ni) {
            const int ix = mi * NFRAG + ni;
            const int gn = n_base + n0 + wn + (ni << 4) + l15;
            const int ln = gn - n_base;
            const int mb = m0 + wm + (mi << 4) + (quad << 2);
            float4v bv = *(const float4v*)(bias + mb);
            float vv[4];
#pragma unroll
            for (int r = 0; r < 4; ++r) {
                float v = acc1[ix][r] + acc2[ix][r] * (1.0f / 2048.0f) + bv[r];
                if (OUTMODE != 2) v = fmaxf(v, 0.f);
                vv[r] = v;
            }
            if (OUTMODE == 0) {
                float4v o = {vv[0], vv[1], vv[2], vv[3]};
                *(float4v*)(outf + (size_t)ln * OC + mb) = o;
            } else if (OUTMODE == 1) {
                half4v hh, ll;
#pragma unroll
                for (int r = 0; r < 4; ++r) {
                    _Float16 h = (_Float16)vv[r];
                    hh[r] = h;
                    ll[r] = (_Float16)((vv[r] - (float)h) * 2048.0f);
                }
                *(half4v*)(outh + (size_t)ln * OC + mb) = hh;
                *(half4v*)(outl + (size_t)ln * OC + mb) = ll;
            } else {
                int b = gn / OHW;
                int p = gn - b * OHW;
#pragma unroll
                for (int r = 0; r < 4; ++r)
                    outf[((size_t)b * OC + mb + r) * OHW + p] = vv[r];
            }
        }
}

// ---------------- fp16x3 MFMA FC2, counted-vmcnt pipeline ------------------
// [512,4096] x [4096,4096]^T, split-K=4, 128x128 tile, K_STEP=64, 8 waves.
__global__ __launch_bounds__(512, 2) void fc2_pipe(
    const _Float16* __restrict__ ah_g, const _Float16* __restrict__ al_g,
    const _Float16* __restrict__ bh_g, const _Float16* __restrict__ bl_g,
    float* __restrict__ part, int kslice)
{
    constexpr int K = 4096, N = 4096;
    const int t    = threadIdx.x;
    const int lane = t & 63;
    const int wid  = t >> 6;
    const int l15  = lane & 15;
    const int quad = lane >> 4;
    const int wm   = (wid >> 2) << 6;
    const int wn   = (wid & 3) << 5;

    const int drow  = lane >> 3;
    const int pslot = lane & 7;
    const int slog  = pslot ^ drow;

    __shared__ __align__(16) _Float16 AhS[2][128 * 64];
    __shared__ __align__(16) _Float16 AlS[2][128 * 64];
    __shared__ __align__(16) _Float16 BhS[2][128 * 64];
    __shared__ __align__(16) _Float16 BlS[2][128 * 64];

    const int n0 = blockIdx.x << 7;
    const int m0 = blockIdx.y << 7;
    const int kbeg = blockIdx.z * kslice;

    float4v acc1[8], acc2[8];
#pragma unroll
    for (int i = 0; i < 8; ++i) {
        acc1[i] = (float4v)(0.f);
        acc2[i] = (float4v)(0.f);
    }

    auto STAGE = [&](int buf, int kb_s) {
#pragma unroll
        for (int ii = 0; ii < 2; ++ii) {
            const int iA = (wid << 1) + ii;
            const size_t ga = (size_t)(m0 + (iA << 3) + drow) * K + kbeg + kb_s + (slog << 3);
            gload_lds16(ah_g + ga, &AhS[buf][iA << 9]);
            gload_lds16(al_g + ga, &AlS[buf][iA << 9]);
            const size_t gb = (size_t)(n0 + (iA << 3) + drow) * K + kbeg + kb_s + (slog << 3);
            gload_lds16(bh_g + gb, &BhS[buf][iA << 9]);
            gload_lds16(bl_g + gb, &BlS[buf][iA << 9]);
        }
    };

    auto COMPUTE = [&](int buf) {
        const _Float16* Ahb = &AhS[buf][0];
        const _Float16* Alb = &AlS[buf][0];
        const _Float16* Bhb = &BhS[buf][0];
        const _Float16* Blb = &BlS[buf][0];
#pragma unroll
        for (int kh2 = 0; kh2 < 2; ++kh2) {
            half8 a_h[4], a_l[4], b_h[2], b_l[2];
#pragma unroll
            for (int i = 0; i < 4; ++i) {
                const int r  = wm + (i << 4) + l15;
                const int sl = ((kh2 << 2) + quad) ^ (r & 7);
                const int off = (r << 6) + (sl << 3);
                a_h[i] = *(const half8*)&Ahb[off];
                a_l[i] = *(const half8*)&Alb[off];
            }
#pragma unroll
            for (int i = 0; i < 2; ++i) {
                const int r  = wn + (i << 4) + l15;
                const int sl = ((kh2 << 2) + quad) ^ (r & 7);
                const int off = (r << 6) + (sl << 3);
                b_h[i] = *(const half8*)&Bhb[off];
                b_l[i] = *(const half8*)&Blb[off];
            }
            __builtin_amdgcn_s_setprio(1);
#pragma unroll
            for (int mi = 0; mi < 4; ++mi)
#pragma unroll
                for (int ni = 0; ni < 2; ++ni) {
                    const int ix = (mi << 1) + ni;
                    acc1[ix] = __builtin_amdgcn_mfma_f32_16x16x32_f16(a_h[mi], b_h[ni], acc1[ix], 0, 0, 0);
                    acc2[ix] = __builtin_amdgcn_mfma_f32_16x16x32_f16(a_h[mi], b_l[ni], acc2[ix], 0, 0, 0);
                    acc2[ix] = __builtin_amdgcn_mfma_f32_16x16x32_f16(a_l[mi], b_h[ni], acc2[ix], 0, 0, 0);
                }
            __builtin_amdgcn_s_setprio(0);
        }
    };

    STAGE(0, 0);
    int cur = 0;
#pragma unroll 1
    for (int kb = 0; kb + 64 < kslice; kb += 64) {
        STAGE(cur ^ 1, kb + 64);
        waitcnt_vm<8>();
        __builtin_amdgcn_s_barrier();
        __builtin_amdgcn_sched_barrier(0);
        COMPUTE(cur);
        __builtin_amdgcn_sched_barrier(0);
        __builtin_amdgcn_s_barrier();
        cur ^= 1;
    }
    waitcnt_vm<0>();
    __builtin_amdgcn_s_barrier();
    __builtin_amdgcn_sched_barrier(0);
    COMPUTE(cur);

    float* po = part + (size_t)blockIdx.z * (512 * 4096);
#pragma unroll
    for (int mi = 0; mi < 4; ++mi)
#pragma unroll
        for (int ni = 0; ni < 2; ++ni) {
            const int ix = (mi << 1) + ni;
            const int gn = n0 + wn + (ni << 4) + l15;
#pragma unroll
            for (int r = 0; r < 4; ++r) {
                const int m = m0 + wm + (mi << 4) + (quad << 2) + r;
                po[(size_t)m * N + gn] = acc1[ix][r] + acc2[ix][r] * (1.0f / 2048.0f);
            }
        }
}

// ---------------- split-K reduce for FC2 (+bias+relu) ----------------------
__global__ __launch_bounds__(256) void fc2_reduce_kernel(
    const float* __restrict__ part, const float* __restrict__ bias,
    float* __restrict__ out)
{
    int idx = blockIdx.x * 256 + threadIdx.x;   // < 512*4096
    if (idx >= 512 * 4096) return;
    const size_t MN = (size_t)512 * 4096;
    float s = 0.f;
#pragma unroll
    for (int zz = 0; zz < 4; ++zz) s += part[zz * MN + idx];
    s += bias[idx & 4095];
    out[idx] = fmaxf(s, 0.f);
}

// ---------------- FC1 fp32 GEMM (K=160, small) -----------------------------
template<bool RELU>
__global__ __launch_bounds__(256) void fc_gemm(
    const float* __restrict__ A, const float* __restrict__ Bw,
    const float* __restrict__ bias, float* __restrict__ out,
    int K, int N)
{
    const int t  = threadIdx.x;
    const int j0 = blockIdx.x << 6;
    const int m0 = blockIdx.y << 7;

    __shared__ __align__(16) float As[16 * 132];
    __shared__ __align__(16) float Bs[16 * 64];

    float acc[8][4];
#pragma unroll
    for (int a = 0; a < 8; ++a)
#pragma unroll
        for (int b = 0; b < 4; ++b) acc[a][b] = 0.f;

    const int a_m  = t >> 2;
    const int a_k  = (t & 3) << 2;
    const int b_j  = t & 63;
    const int b_k0 = (t >> 6) << 2;
    const int ms = (t >> 4) << 3;
    const int js = (t & 15) << 2;

    for (int kb0 = 0; kb0 < K; kb0 += 16) {
#pragma unroll
        for (int r = 0; r < 2; ++r) {
            int m = m0 + a_m + (r << 6);
            float4 av = *(const float4*)(A + (size_t)m * K + kb0 + a_k);
            As[(a_k + 0) * 132 + a_m + (r << 6)] = av.x;
            As[(a_k + 1) * 132 + a_m + (r << 6)] = av.y;
            As[(a_k + 2) * 132 + a_m + (r << 6)] = av.z;
            As[(a_k + 3) * 132 + a_m + (r << 6)] = av.w;
        }
        {
            float4 bv = *(const float4*)(Bw + (size_t)(j0 + b_j) * K + kb0 + b_k0);
            Bs[(b_k0 + 0) * 64 + b_j] = bv.x;
            Bs[(b_k0 + 1) * 64 + b_j] = bv.y;
            Bs[(b_k0 + 2) * 64 + b_j] = bv.z;
            Bs[(b_k0 + 3) * 64 + b_j] = bv.w;
        }
        __syncthreads();
#pragma unroll
        for (int kk = 0; kk < 16; ++kk) {
            float4 A0 = *(const float4*)&As[kk * 132 + ms];
            float4 A1 = *(const float4*)&As[kk * 132 + ms + 4];
            float4 B0 = *(const float4*)&Bs[(kk << 6) + js];
            float av[8] = {A0.x, A0.y, A0.z, A0.w, A1.x, A1.y, A1.z, A1.w};
            float bv[4] = {B0.x, B0.y, B0.z, B0.w};
#pragma unroll
            for (int mm = 0; mm < 8; ++mm)
#pragma unroll
                for (int jj = 0; jj < 4; ++jj)
                    acc[mm][jj] = fmaf(av[mm], bv[jj], acc[mm][jj]);
        }
        __syncthreads();
    }
    float4 b4 = *(const float4*)(bias + j0 + js);
#pragma unroll
    for (int mm = 0; mm < 8; ++mm) {
        float4 o;
        o.x = acc[mm][0] + b4.x;
        o.y = acc[mm][1] + b4.y;
        o.z = acc[mm][2] + b4.z;
        o.w = acc[mm][3] + b4.w;
        if (RELU) {
            o.x = fmaxf(o.x, 0.f); o.y = fmaxf(o.y, 0.f);
            o.z = fmaxf(o.z, 0.f); o.w = fmaxf(o.w, 0.f);
        }
        *(float4*)(out + (size_t)(m0 + ms + mm) * N + j0 + js) = o;
    }
}

// ---------------- squash of primary caps -----------------------------------
__global__ __launch_bounds__(256) void squash_kernel(
    const float* __restrict__ p, float* __restrict__ u)
{
    int cap = blockIdx.x * 256 + threadIdx.x;   // < 512*512
    if (cap >= 512 * 512) return;
    const float4* pi = (const float4*)(p + (size_t)cap * 8);
    float4 a = pi[0], b = pi[1];
    float sq = a.x * a.x + a.y * a.y + a.z * a.z + a.w * a.w
             + b.x * b.x + b.y * b.y + b.z * b.z + b.w * b.w;
    float f  = sq / (1.f + sq);
    float rs = sqrtf(sq + 1e-8f);
    float4 o0, o1;
    o0.x = (f * a.x) / rs; o0.y = (f * a.y) / rs;
    o0.z = (f * a.z) / rs; o0.w = (f * a.w) / rs;
    o1.x = (f * b.x) / rs; o1.y = (f * b.y) / rs;
    o1.z = (f * b.z) / rs; o1.w = (f * b.w) / rs;
    float4* po = (float4*)(u + (size_t)cap * 8);
    po[0] = o0; po[1] = o1;
}

// ---------------- x_hat precompute: xh[o][v][b][i] (half-batch) ------------
__global__ __launch_bounds__(256) void xhat_kernel(
    const float* __restrict__ u,   // [256][512][8] (half-batch base)
    const float* __restrict__ Wr,  // [10][512][16][8]
    float* __restrict__ xh)        // [10][16][256][512]
{
    const int t  = threadIdx.x;
    const int o  = blockIdx.y;
    const int i0 = blockIdx.x << 5;
    const int ii = t & 31;
    const int bs = t >> 5;                 // 0..7

    __shared__ __align__(16) float wsh[32 * 132];

    const float* wsrc = Wr + ((size_t)o * 512 + i0) * 128;
    for (int idx = t; idx < 1024; idx += 256) {
        float4 wv = *(const float4*)(wsrc + idx * 4);
        int r = (idx * 4) >> 7;
        int c = (idx * 4) & 127;
        *(float4*)&wsh[r * 132 + c] = wv;
    }
    __syncthreads();

    const int i = i0 + ii;
    const float* wrow = &wsh[ii * 132];

#pragma unroll
    for (int cch = 0; cch < 4; ++cch) {
        float uu[8][8];
#pragma unroll
        for (int l = 0; l < 8; ++l) {
            int b = bs + (cch << 6) + (l << 3);
            float4 u0 = *(const float4*)(u + (size_t)b * 4096 + i * 8);
            float4 u1 = *(const float4*)(u + (size_t)b * 4096 + i * 8 + 4);
            uu[l][0] = u0.x; uu[l][1] = u0.y; uu[l][2] = u0.z; uu[l][3] = u0.w;
            uu[l][4] = u1.x; uu[l][5] = u1.y; uu[l][6] = u1.z; uu[l][7] = u1.w;
        }
#pragma unroll
        for (int v = 0; v < 16; ++v) {
            float4 w0 = *(const float4*)&wrow[v << 3];
            float4 w1 = *(const float4*)&wrow[(v << 3) + 4];
            float acc[8];
#pragma unroll
            for (int l = 0; l < 8; ++l) {
                acc[l] = uu[l][0] * w0.x + uu[l][1] * w0.y + uu[l][2] * w0.z + uu[l][3] * w0.w
                       + uu[l][4] * w1.x + uu[l][5] * w1.y + uu[l][6] * w1.z + uu[l][7] * w1.w;
            }
#pragma unroll
            for (int l = 0; l < 8; ++l) {
                int b = bs + (cch << 6) + (l << 3);
                xh[(((size_t)(o << 4) + v) * 256 + b) * 512 + i] = acc[l];
            }
        }
    }
}

// ---------------- routing from precomputed x_hat (shuffle-free) ------------
__global__ __launch_bounds__(256) void routing2_kernel(
    const float* __restrict__ xh,  // [10][16][256][512]
    float* __restrict__ vout)      // [256][160] (half base)
{
    const int b = blockIdx.x;
    const int t = threadIdx.x;

    __shared__ __align__(16) float b_s[5120];
    __shared__ __align__(16) float c_s[5120];
    __shared__ float s_s[160];
    __shared__ float v_s[160];

    for (int idx = t; idx < 5120; idx += 256) b_s[idx] = 0.f;
    __syncthreads();

    const int o_t = t >> 4;
    const float* xrow = xh + ((size_t)t * 256 + b) * 512;

    for (int it = 0; it < 3; ++it) {
        for (int i = t; i < 512; i += 256) {
            float bv[10], mx = -3.4e38f;
#pragma unroll
            for (int o = 0; o < 10; ++o) { bv[o] = b_s[(o << 9) + i]; mx = fmaxf(mx, bv[o]); }
            float sum = 0.f;
#pragma unroll
            for (int o = 0; o < 10; ++o) { bv[o] = expf(bv[o] - mx); sum += bv[o]; }
            float inv = 1.f / sum;
#pragma unroll
            for (int o = 0; o < 10; ++o) c_s[(o << 9) + i] = bv[o] * inv;
        }
        __syncthreads();
        if (t < 160) {
            const float* cp = c_s + (o_t << 9);
            float4 a0 = {0.f, 0.f, 0.f, 0.f};
            float4 a1 = {0.f, 0.f, 0.f, 0.f};
            for (int i = 0; i < 512; i += 8) {
                float4 x0 = *(const float4*)(xrow + i);
                float4 x1 = *(const float4*)(xrow + i + 4);
                float4 c0 = *(const float4*)(cp + i);
                float4 c1 = *(const float4*)(cp + i + 4);
                a0.x = fmaf(x0.x, c0.x, a0.x); a0.y = fmaf(x0.y, c0.y, a0.y);
                a0.z = fmaf(x0.z, c0.z, a0.z); a0.w = fmaf(x0.w, c0.w, a0.w);
                a1.x = fmaf(x1.x, c1.x, a1.x); a1.y = fmaf(x1.y, c1.y, a1.y);
                a1.z = fmaf(x1.z, c1.z, a1.z); a1.w = fmaf(x1.w, c1.w, a1.w);
            }
            s_s[t] = (a0.x + a0.y) + (a0.z + a0.w) + (a1.x + a1.y) + (a1.z + a1.w);
        }
        __syncthreads();
        if (t < 10) {
            float tv[16], sq = 0.f;
#pragma unroll
            for (int v = 0; v < 16; ++v) { tv[v] = s_s[(t << 4) + v]; sq = fmaf(tv[v], tv[v], sq); }
            float f  = sq / (1.f + sq);
            float rs = sqrtf(sq + 1e-8f);
#pragma unroll
            for (int v = 0; v < 16; ++v) v_s[(t << 4) + v] = (f * tv[v]) / rs;
        }
        __syncthreads();
        if (it < 2) {
            for (int p = t; p < 5120; p += 256) {
                int o = p >> 9;
                int i = p & 511;
                const float* xp = xh + ((size_t)(o << 4) * 256 + b) * 512 + i;
                float acc = b_s[p];
#pragma unroll
                for (int v = 0; v < 16; ++v)
                    acc = fmaf(v_s[(o << 4) + v], xp[(size_t)v * (256 * 512)], acc);
                b_s[p] = acc;
            }
            __syncthreads();
        }
    }

    for (int idx = t; idx < 160; idx += 256) vout[(size_t)b * 160 + idx] = v_s[idx];
}

// ---------------- FC3: [512,4096] x [10,4096]^T + b -> [512,10] ------------
__global__ __launch_bounds__(256) void fc3_kernel(
    const float* __restrict__ f, const float* __restrict__ w,
    const float* __restrict__ bias, float* __restrict__ out)
{
    const int n = blockIdx.x;
    const int t = threadIdx.x;
    const int lane = t & 63, wv = t >> 6;
    const float* fr = f + (size_t)n * 4096;
    float p[10];
#pragma unroll
    for (int j = 0; j < 10; ++j) p[j] = 0.f;
    for (int k = t; k < 4096; k += 256) {
        float x = fr[k];
#pragma unroll
        for (int j = 0; j < 10; ++j) p[j] = fmaf(x, w[j * 4096 + k], p[j]);
    }
    __shared__ float red[4 * 10];
#pragma unroll
    for (int j = 0; j < 10; ++j) {
        float x = p[j];
        for (int off = 32; off > 0; off >>= 1) x += __shfl_xor(x, off);
        p[j] = x;
    }
    if (lane == 0) {
#pragma unroll
        for (int j = 0; j < 10; ++j) red[wv * 10 + j] = p[j];
    }
    __syncthreads();
    if (t < 10)
        out[(size_t)n * 10 + t] = red[t] + red[10 + t] + red[20 + t] + red[30 + t] + bias[t];
}

// ===========================================================================
extern "C" void kernel_launch(void* const* d_in, const int* in_sizes, int n_in,
                              void* d_out, int out_size, void* d_ws, size_t ws_size,
                              hipStream_t stream)
{
    const float* x   = (const float*)d_in[0];
    const float* w1  = (const float*)d_in[1];
    const float* b1  = (const float*)d_in[2];
    const float* w2  = (const float*)d_in[3];
    const float* b2  = (const float*)d_in[4];
    const float* w3  = (const float*)d_in[5];
    const float* b3  = (const float*)d_in[6];
    const float* w4  = (const float*)d_in[7];
    const float* b4  = (const float*)d_in[8];
    const float* w5  = (const float*)d_in[9];
    const float* b5  = (const float*)d_in[10];
    const float* wp  = (const float*)d_in[11];
    const float* bp  = (const float*)d_in[12];
    const float* Wr  = (const float*)d_in[13];
    const float* fw1 = (const float*)d_in[14];
    const float* fb1 = (const float*)d_in[15];
    const float* fw2 = (const float*)d_in[16];
    const float* fb2 = (const float*)d_in[17];
    const float* fw3 = (const float*)d_in[18];
    const float* fb3 = (const float*)d_in[19];
    float* outp = (float*)d_out;

    char* w = (char*)d_ws;
    // ---- static region: K-padded split weights + zero page -----------------
    _Float16* w2h  = (_Float16*)(w + 115605504);   //   458,752
    _Float16* w2l  = (_Float16*)(w + 116064256);   //   458,752 -> 116,523,008
    _Float16* w3h  = (_Float16*)(w + 116523008);   // 1,769,472
    _Float16* w3l  = (_Float16*)(w + 118292480);   //        -> 120,061,952
    _Float16* w4h  = (_Float16*)(w + 120061952);   // 2,654,208
    _Float16* w4l  = (_Float16*)(w + 122716160);   //        -> 125,370,368
    _Float16* w5h  = (_Float16*)(w + 125370368);   // 1,769,472
    _Float16* w5l  = (_Float16*)(w + 127139840);   //        -> 128,909,312
    _Float16* wph  = (_Float16*)(w + 128909312);   //   524,288
    _Float16* wpl  = (_Float16*)(w + 129433600);   //        -> 129,957,888
    float*    zp   = (float*)(w + 129957888);      //       256 -> 129,958,144

    // ---- dynamic region timeline (unchanged from proven r9) ----------------
    _Float16* p1h  = (_Float16*)(w + 0);           // 19,267,584
    _Float16* p1l  = (_Float16*)(w + 19267584);    // ends 38,535,168
    float*    a2   = (float*)(w + 38535168);       // 51,380,224 (half batch), ends 89,915,392
    _Float16* p2h  = (_Float16*)(w + 89915392);    // 12,845,056
    _Float16* p2l  = (_Float16*)(w + 102760448);   // ends 115,605,504
    _Float16* a3h  = (_Float16*)(w + 0);           // 19,267,584
    _Float16* a3l  = (_Float16*)(w + 19267584);    // ends 38,535,168
    _Float16* a4h  = (_Float16*)(w + 38535168);    // 19,267,584
    _Float16* a4l  = (_Float16*)(w + 57802752);    // ends 77,070,336
    float*    a5   = (float*)(w + 0);              // 25,690,112
    _Float16* p3h  = (_Float16*)(w + 25690112);    // 6,553,600
    _Float16* p3l  = (_Float16*)(w + 32243712);    // ends 38,797,312 (a4 dead by then)
    float*    pc   = (float*)(w + 0);              //  8,388,608
    float*    u    = (float*)(w + 8388608);        //  8,388,608, ends 16,777,216
    float*    vcap = (float*)(w + 16777216);       //    327,680, ends 17,104,896
    float*    xh   = (float*)(w + 17104896);       // 83,886,080, ends 100,990,976

    // ---- FC phase layout (xh dead after routing; audited disjoint) --------
    float*    f1   = (float*)(w + 17104896);       //  8,388,608, ends 25,493,504
    _Float16* fw2h = (_Float16*)(w + 33882112);    // 33,554,432, ends 67,436,544
    _Float16* fw2l = (_Float16*)(w + 67436544);    // 33,554,432, ends 100,990,976
    _Float16* f1h  = (_Float16*)(w + 100990976);   //  4,194,304
    _Float16* f1l  = (_Float16*)(w + 105185280);   //  ends 109,379,584
    float*    part = (float*)(w + 0);              // 33,554,432 (4 slices)
    float*    f2   = (float*)(w + 33882112);       //  8,388,608 (fw2h dead at reduce)

    // ---- zero page + pre-split weights (reordered (kh,kw,ic), K-padded) ---
    zero_kernel<<<dim3(1), dim3(64), 0, stream>>>(zp);
    wsplit_pad_kernel<<<dim3(896),  dim3(256), 0, stream>>>(w2, w2h, w2l,  96, 9,  864,  896,  229376);
    wsplit_pad_kernel<<<dim3(3456), dim3(256), 0, stream>>>(w3, w3h, w3l, 256, 9, 2304, 2304,  884736);
    wsplit_pad_kernel<<<dim3(5184), dim3(256), 0, stream>>>(w4, w4h, w4l, 384, 9, 3456, 3456, 1327104);
    wsplit_pad_kernel<<<dim3(3456), dim3(256), 0, stream>>>(w5, w5h, w5l, 384, 9, 3456, 3456,  884736);
    wsplit_pad_kernel<<<dim3(1024), dim3(256), 0, stream>>>(wp, wph, wpl, 256, 4, 1024, 1024,  262144);

    // conv1 + relu + pool1 : x -> p1 split NHWC [512,14,14,96]
    conv1_pool_nhwc<<<dim3(37632), dim3(256), 0, stream>>>(x, w1, b1, p1h, p1l);

    // conv2 + relu (fp32 NHWC out), two batch halves, each followed by pool2
    conv_pipe<96, 14, 14, 3, 1, 256, 128, 0><<<dim3(392, 2), dim3(512), 0, stream>>>(
        p1h, p1l, w2h, w2l, b2, zp, a2, nullptr, nullptr, 0);
    maxpool_nhwc_split<256, 256, 14, 14, 7, 7, 3, 2, 1><<<dim3(12544), dim3(256), 0, stream>>>(
        a2, p2h, p2l);
    conv_pipe<96, 14, 14, 3, 1, 256, 128, 0><<<dim3(392, 2), dim3(512), 0, stream>>>(
        p1h, p1l, w2h, w2l, b2, zp, a2, nullptr, nullptr, 50176);
    maxpool_nhwc_split<256, 256, 14, 14, 7, 7, 3, 2, 1><<<dim3(12544), dim3(256), 0, stream>>>(
        a2, p2h + (size_t)3211264, p2l + (size_t)3211264);

    // conv3 + relu : p2 -> a3 split NHWC [512,7,7,384]
    conv_pipe<256, 7, 7, 3, 1, 384, 128, 1><<<dim3(196, 3), dim3(512), 0, stream>>>(
        p2h, p2l, w3h, w3l, b3, zp, nullptr, a3h, a3l, 0);
    // conv4 + relu : a3 -> a4 split NHWC [512,7,7,384]
    conv_pipe<384, 7, 7, 3, 1, 384, 128, 1><<<dim3(196, 3), dim3(512), 0, stream>>>(
        a3h, a3l, w4h, w4l, b4, zp, nullptr, a4h, a4l, 0);
    // conv5 + relu : a4 -> a5 fp32 NHWC [512,7,7,256]
    conv_pipe<384, 7, 7, 3, 1, 256, 128, 0><<<dim3(196, 2), dim3(512), 0, stream>>>(
        a4h, a4l, w5h, w5l, b5, zp, a5, nullptr, nullptr, 0);
    // pool3 : a5 -> p3 split NHWC [512,5,5,256]
    maxpool_nhwc_split<512, 256, 7, 7, 5, 5, 3, 1, 0><<<dim3(12800), dim3(256), 0, stream>>>(
        a5, p3h, p3l);
    // primary caps conv (k2,s1,p0, no relu) : p3 -> pc fp32 NCHW [512,256,4,4]
    conv_pipe<256, 5, 5, 2, 0, 256, 64, 2><<<dim3(128, 2), dim3(512), 0, stream>>>(
        p3h, p3l, wph, wpl, bp, zp, pc, nullptr, nullptr, 0);
    // squash : pc -> u [512,512,8]
    squash_kernel<<<dim3(1024), dim3(256), 0, stream>>>(pc, u);

    // dynamic routing via precomputed x_hat, two half-batches
    for (int h = 0; h < 2; ++h) {
        const float* uh = u + (size_t)h * 256 * 4096;
        float* vh = vcap + (size_t)h * 256 * 160;
        xhat_kernel<<<dim3(16, 10), dim3(256), 0, stream>>>(uh, Wr, xh);
        routing2_kernel<<<dim3(256), dim3(256), 0, stream>>>(xh, vh);
    }

    // one-time fw2 split to f16 hi/lo (xh region dead now)
    split_kernel<<<dim3(65536), dim3(256), 0, stream>>>(fw2, fw2h, fw2l, 16777216);

    // FC1 + relu (fp32, K=160) : vcap -> f1 [512,4096]
    fc_gemm<true><<<dim3(64, 4), dim3(256), 0, stream>>>(vcap, fw1, fb1, f1, 160, 4096);
    // split f1
    split_kernel<<<dim3(8192), dim3(256), 0, stream>>>(f1, f1h, f1l, 2097152);
    // FC2 pipelined split-K=4 : f1s x fw2s -> part [4,512,4096]
    fc2_pipe<<<dim3(32, 4, 4), dim3(512), 0, stream>>>(f1h, f1l, fw2h, fw2l, part, 1024);
    // reduce + bias + relu : part -> f2 [512,4096]
    fc2_reduce_kernel<<<dim3(8192), dim3(256), 0, stream>>>(part, fb2, f2);
    // FC3 : f2 -> out [512,10]
    fc3_kernel<<<dim3(512), dim3(256), 0, stream>>>(f2, fw3, fb3, outp);
}

// Round 6
// 1444.114 us; speedup vs baseline: 1.2382x; 1.2382x over previous
//
#include <hip/hip_runtime.h>
#include <math.h>

// ===========================================================================
// AlexCapsNet forward. Big convs + FC2 via fp16x3-split MFMA (16x16x32_f16).
// a = ah + al/2048 (al stored pre-scaled by 2048 to stay in f16 normal range).
// C = sum ah*bh  +  (sum ah*bl + al*bh) / 2048      (al*bl dropped, ~2^-22)
//
// Round 12 = r11 with the a2h/a2l allocation bug fixed. r11's failure
// (absmax 4.5e-3) was a ws sizing error: a2 planes sized in ELEMENTS
// (12,845,056) instead of BYTES (25,690,112) -> conv2 hi-plane writes for
// ln>=25088 clobbered the lo-plane. Fixed: a2h@38,535,168 (25,690,112 B),
// a2l@64,225,280 (ends 89,915,392 = p2h start). All pairs re-audited.
//
// Design (r9 base, proven 1403us, + r11 additions):
//  (1) XCD-chunked bijective blockIdx swizzle (T1/m204), n-fastest logical
//      order: A-tile L2-resident + neighbor-block im2col tap reuse in L2.
//  (2) conv2/conv5 emit split-f16 NHWC; pools read split pairs and re-split
//      (recon error ~2^-24 rel). Saves ~90MB of pool-chain traffic.
// r10's deep pipeline regressed (1 block/CU killed cross-block overlap) and
// stays reverted.
// ===========================================================================

#define BATCH 512

typedef _Float16 half8  __attribute__((ext_vector_type(8)));
typedef _Float16 half4v __attribute__((ext_vector_type(4)));
typedef float   float4v __attribute__((ext_vector_type(4)));

// ---------------- global->LDS 16B DMA helper -------------------------------
__device__ __forceinline__ void gload_lds16(const void* g, void* l)
{
    __builtin_amdgcn_global_load_lds(
        (const __attribute__((address_space(1))) unsigned int*)g,
        (__attribute__((address_space(3))) unsigned int*)l,
        16, 0, 0);
}

// ---------------- zero page ------------------------------------------------
__global__ __launch_bounds__(64) void zero_kernel(float* __restrict__ z)
{
    z[threadIdx.x] = 0.f;
}

// ---------------- fp32 -> (hi f16, lo f16*2048) split (linear) -------------
__global__ __launch_bounds__(256) void split_kernel(
    const float* __restrict__ src, _Float16* __restrict__ hi,
    _Float16* __restrict__ lo, int n)
{
    int idx = blockIdx.x * 256 + threadIdx.x;
    if (idx >= n) return;
    float v = src[idx];
    _Float16 h = (_Float16)v;
    hi[idx] = h;
    lo[idx] = (_Float16)((v - (float)h) * 2048.0f);
}

// -------- weight reorder [oc][ic][kh][kw] -> [oc][(kh,kw,ic) padded] + split
__global__ __launch_bounds__(256) void wsplit_pad_kernel(
    const float* __restrict__ src, _Float16* __restrict__ hi,
    _Float16* __restrict__ lo, int IC, int KK, int K, int KP, int total)
{
    int idx = blockIdx.x * 256 + threadIdx.x;   // idx = oc*KP + k
    if (idx >= total) return;
    int k  = idx % KP;
    int oc = idx / KP;
    float v = 0.f;
    if (k < K) {
        int khkw = k / IC;
        int ic   = k - khkw * IC;
        v = src[((size_t)(oc * IC + ic)) * KK + khkw];
    }
    _Float16 h = (_Float16)v;
    hi[idx] = h;
    lo[idx] = (_Float16)((v - (float)h) * 2048.0f);
}

// ---------------- conv1(1->96,3x3,p1) + relu + maxpool(3,2,1) fused --------
// Output: NHWC split f16 hi/lo [512][14][14][96]
__global__ __launch_bounds__(256) void conv1_pool_nhwc(
    const float* __restrict__ x, const float* __restrict__ w1,
    const float* __restrict__ b1, _Float16* __restrict__ oh_,
    _Float16* __restrict__ ol_)
{
    int idx = blockIdx.x * 256 + threadIdx.x;   // = ((n*14+oh)*14+ow)*96+oc
    if (idx >= 512 * 14 * 14 * 96) return;
    int oc = idx % 96; int t1 = idx / 96;
    int ow = t1 % 14;  int t2 = t1 / 14;
    int oh = t2 % 14;  int n  = t2 / 14;
    const float* xi = x + n * 784;
    float w[9];
#pragma unroll
    for (int i = 0; i < 9; ++i) w[i] = w1[oc * 9 + i];
    float bias = b1[oc];
    float best = -3.4e38f;
#pragma unroll
    for (int dy = 0; dy < 3; ++dy) {
        int ph = oh * 2 - 1 + dy;
        if ((unsigned)ph >= 28u) continue;
#pragma unroll
        for (int dx = 0; dx < 3; ++dx) {
            int pw = ow * 2 - 1 + dx;
            if ((unsigned)pw >= 28u) continue;
            float s = bias;
#pragma unroll
            for (int ky = 0; ky < 3; ++ky) {
                int iy = ph - 1 + ky;
                if ((unsigned)iy >= 28u) continue;
#pragma unroll
                for (int kx = 0; kx < 3; ++kx) {
                    int ix = pw - 1 + kx;
                    if ((unsigned)ix >= 28u) continue;
                    s = fmaf(w[ky * 3 + kx], xi[iy * 28 + ix], s);
                }
            }
            s = fmaxf(s, 0.f);
            best = fmaxf(best, s);
        }
    }
    _Float16 h = (_Float16)best;
    oh_[idx] = h;
    ol_[idx] = (_Float16)((best - (float)h) * 2048.0f);
}

// ---------------- NHWC maxpool (split f16 in) -> split f16 out -------------
template<int NB, int C, int H, int W, int OH, int OW, int KS, int STR, int PADP>
__global__ __launch_bounds__(256) void maxpool_resplit(
    const _Float16* __restrict__ ih_, const _Float16* __restrict__ il_,
    _Float16* __restrict__ po, _Float16* __restrict__ pl)
{
    constexpr int TOTAL = NB * OH * OW * C;
    int idx = blockIdx.x * 256 + threadIdx.x;   // = ((n*OH+oh)*OW+ow)*C+c
    if (idx >= TOTAL) return;
    int c  = idx % C;  int t1 = idx / C;
    int ow = t1 % OW;  int t2 = t1 / OW;
    int oh = t2 % OH;  int n  = t2 / OH;
    const size_t base = (size_t)n * (H * W * C) + c;
    float best = -3.4e38f;
#pragma unroll
    for (int dy = 0; dy < KS; ++dy) {
        int ihh = oh * STR - PADP + dy;
        if ((unsigned)ihh >= (unsigned)H) continue;
#pragma unroll
        for (int dx = 0; dx < KS; ++dx) {
            int iww = ow * STR - PADP + dx;
            if ((unsigned)iww >= (unsigned)W) continue;
            const size_t off = base + (size_t)(ihh * W + iww) * C;
            float v = (float)ih_[off] + (float)il_[off] * (1.0f / 2048.0f);
            best = fmaxf(best, v);
        }
    }
    _Float16 h = (_Float16)best;
    po[idx] = h;
    pl[idx] = (_Float16)((best - (float)h) * 2048.0f);
}

// ---------------- fp16x3 MFMA implicit-GEMM conv, DMA + swizzled LDS -------
// M = OC (tile 128), N = batch*OHW (tile NT), K = KH*KH*IC (step 64).
// 1D grid NWG = NBN*MB with XCD-chunked bijective swizzle (m204); logical
// order n-fastest -> each XCD sees a contiguous n-range at ~one m-row:
// A-tile L2-resident, neighbor-block tap reuse in L2.
// LDS rows = 64 halfs (128 B, 8 slots of 16 B), phys_slot = slot ^ (row&7).
// DMA source pre-inverse-swizzled per lane. OOB taps DMA from zero page.
// OUTMODE: 0 = fp32 NHWC + relu, 1 = split f16 NHWC + relu, 2 = fp32 NCHW.
template<int IC, int H, int W, int KH, int PAD, int OC, int NT, int NBN, int OUTMODE>
__global__ __launch_bounds__(256, 2) void conv_dma(
    const _Float16* __restrict__ inh, const _Float16* __restrict__ inl,
    const _Float16* __restrict__ whi, const _Float16* __restrict__ wlo,
    const float* __restrict__ bias, const float* __restrict__ zpage,
    float* __restrict__ outf, _Float16* __restrict__ outh,
    _Float16* __restrict__ outl, int n_base)
{
    constexpr int OH  = H + 2 * PAD - KH + 1;
    constexpr int OW  = W + 2 * PAD - KH + 1;
    constexpr int OHW = OH * OW;
    constexpr int K   = IC * KH * KH;
    constexpr int KP  = (K + 63) & ~63;
    constexpr int NFRAG = NT / 32;           // per-wave N fragments
    constexpr int NBI   = NT / 32;           // B DMA instrs per wave
    constexpr bool UNIF = (IC % 64 == 0) && (KP == K);
    constexpr int HWIC = H * W * IC;
    constexpr int MB   = OC >> 7;
    constexpr int NWG  = NBN * MB;

    const int t    = threadIdx.x;
    const int lane = t & 63;
    const int wid  = t >> 6;
    const int l15  = lane & 15;
    const int quad = lane >> 4;
    const int wm   = (wid >> 1) << 6;        // 0 / 64
    const int wn   = (wid & 1) * (NT / 2);

    const int drow  = lane >> 3;             // row within 8-row DMA group
    const int pslot = lane & 7;              // physical slot this lane fills
    const int slog  = pslot ^ drow;          // logical slot to fetch

    __shared__ __align__(16) _Float16 Ah[128 * 64];
    __shared__ __align__(16) _Float16 Al[128 * 64];
    __shared__ __align__(16) _Float16 Bh[NT * 64];
    __shared__ __align__(16) _Float16 Bl[NT * 64];

    // ---- XCD-chunked bijective swizzle (m204), n-fastest logical order ----
    const int bid = blockIdx.x;
    constexpr int q = NWG >> 3, rr = NWG & 7;
    const int xcd = bid & 7, boff = bid >> 3;
    const int lg = (xcd < rr) ? (xcd * (q + 1) + boff)
                              : (rr * (q + 1) + (xcd - rr) * q + boff);
    const int n0 = (lg % NBN) * NT;
    const int m0 = (lg / NBN) << 7;

    float4v acc1[4 * NFRAG], acc2[4 * NFRAG];
#pragma unroll
    for (int i = 0; i < 4 * NFRAG; ++i) {
        acc1[i] = (float4v)(0.f);
        acc2[i] = (float4v)(0.f);
    }

    // per-lane B geometry (per DMA instr)
    int bU[NBI], ohU[NBI], owU[NBI];
#pragma unroll
    for (int ii = 0; ii < NBI; ++ii) {
        int nl = ((wid * NBI + ii) << 3) + drow;
        int gn = n_base + n0 + nl;
        int b  = gn / OHW;
        int p  = gn - b * OHW;
        int o  = p / OW;
        bU[ii] = b; ohU[ii] = o; owU[ii] = p - o * OW;
    }

    int khkw = 0, icb = 0;
    for (int kb = 0; kb < KP; kb += 64) {
        // ---- A DMA (weights, linear rows of stride KP) ----
#pragma unroll
        for (int ii = 0; ii < 4; ++ii) {
            const int iA = (wid << 2) + ii;
            const size_t go = (size_t)(m0 + (iA << 3) + drow) * KP + kb + (slog << 3);
            gload_lds16(whi + go, &Ah[(size_t)iA << 9]);
            gload_lds16(wlo + go, &Al[(size_t)iA << 9]);
        }
        // ---- B DMA (im2col gather via per-lane source) ----
        if constexpr (UNIF) {
            const int kh = khkw / KH;
            const int kw = khkw - kh * KH;
#pragma unroll
            for (int ii = 0; ii < NBI; ++ii) {
                const int iB = wid * NBI + ii;
                const int ih = ohU[ii] + kh - PAD;
                const int iw = owU[ii] + kw - PAD;
                const bool ok = ((unsigned)ih < (unsigned)H) && ((unsigned)iw < (unsigned)W);
                const size_t off = (size_t)bU[ii] * HWIC + (ih * W + iw) * IC + icb + (slog << 3);
                const _Float16* sh = ok ? inh + off : (const _Float16*)zpage;
                const _Float16* sl = ok ? inl + off : (const _Float16*)zpage;
                gload_lds16(sh, &Bh[(size_t)iB << 9]);
                gload_lds16(sl, &Bl[(size_t)iB << 9]);
            }
            icb += 64;
            if (icb == IC) { icb = 0; ++khkw; }
        } else {
            const int kpl = kb + (slog << 3);        // per-lane k
            const int kkl = kpl / IC;
            const int icl = kpl - kkl * IC;
            const int khl = kkl / KH;
            const int kwl = kkl - khl * KH;
#pragma unroll
            for (int ii = 0; ii < NBI; ++ii) {
                const int iB = wid * NBI + ii;
                const int ih = ohU[ii] + khl - PAD;
                const int iw = owU[ii] + kwl - PAD;
                const bool ok = (kpl < K) && ((unsigned)ih < (unsigned)H) &&
                                ((unsigned)iw < (unsigned)W);
                const size_t off = (size_t)bU[ii] * HWIC + (ih * W + iw) * IC + icl;
                const _Float16* sh = ok ? inh + off : (const _Float16*)zpage;
                const _Float16* sl = ok ? inl + off : (const _Float16*)zpage;
                gload_lds16(sh, &Bh[(size_t)iB << 9]);
                gload_lds16(sl, &Bl[(size_t)iB << 9]);
            }
        }
        __syncthreads();                             // drains vmcnt -> tile ready
        // ---- compute: two k-halves of 32 ----
#pragma unroll
        for (int kh2 = 0; kh2 < 2; ++kh2) {
            half8 a_h[4], a_l[4], b_h[NFRAG], b_l[NFRAG];
#pragma unroll
            for (int i = 0; i < 4; ++i) {
                const int r  = wm + (i << 4) + l15;
                const int sl = ((kh2 << 2) + quad) ^ (r & 7);
                const int off = (r << 6) + (sl << 3);
                a_h[i] = *(const half8*)&Ah[off];
                a_l[i] = *(const half8*)&Al[off];
            }
#pragma unroll
            for (int i = 0; i < NFRAG; ++i) {
                const int r  = wn + (i << 4) + l15;
                const int sl = ((kh2 << 2) + quad) ^ (r & 7);
                const int off = (r << 6) + (sl << 3);
                b_h[i] = *(const half8*)&Bh[off];
                b_l[i] = *(const half8*)&Bl[off];
            }
#pragma unroll
            for (int mi = 0; mi < 4; ++mi)
#pragma unroll
                for (int ni = 0; ni < NFRAG; ++ni) {
                    const int ix = mi * NFRAG + ni;
                    acc1[ix] = __builtin_amdgcn_mfma_f32_16x16x32_f16(a_h[mi], b_h[ni], acc1[ix], 0, 0, 0);
                    acc2[ix] = __builtin_amdgcn_mfma_f32_16x16x32_f16(a_h[mi], b_l[ni], acc2[ix], 0, 0, 0);
                    acc2[ix] = __builtin_amdgcn_mfma_f32_16x16x32_f16(a_l[mi], b_h[ni], acc2[ix], 0, 0, 0);
                }
        }
        __syncthreads();                             // reads done before next DMA
    }
    // ---- epilogue: combine, bias(+relu), NHWC stores ----
#pragma unroll
    for (int mi = 0; mi < 4; ++mi)
#pragma unroll
        for (int ni = 0; ni < NFRAG; ++ni) {
            const int ix = mi * NFRAG + ni;
            const int gn = n_base + n0 + wn + (ni << 4) + l15;
            const int ln = gn - n_base;
            const int mb = m0 + wm + (mi << 4) + (quad << 2);
            float4v bv = *(const float4v*)(bias + mb);
            float vv[4];
#pragma unroll
            for (int r = 0; r < 4; ++r) {
                float v = acc1[ix][r] + acc2[ix][r] * (1.0f / 2048.0f) + bv[r];
                if (OUTMODE != 2) v = fmaxf(v, 0.f);
                vv[r] = v;
            }
            if (OUTMODE == 0) {
                float4v o = {vv[0], vv[1], vv[2], vv[3]};
                *(float4v*)(outf + (size_t)ln * OC + mb) = o;
            } else if (OUTMODE == 1) {
                half4v hh, ll;
#pragma unroll
                for (int r = 0; r < 4; ++r) {
                    _Float16 h = (_Float16)vv[r];
                    hh[r] = h;
                    ll[r] = (_Float16)((vv[r] - (float)h) * 2048.0f);
                }
                *(half4v*)(outh + (size_t)ln * OC + mb) = hh;
                *(half4v*)(outl + (size_t)ln * OC + mb) = ll;
            } else {
                int b = gn / OHW;
                int p = gn - b * OHW;
#pragma unroll
                for (int r = 0; r < 4; ++r)
                    outf[((size_t)b * OC + mb + r) * OHW + p] = vv[r];
            }
        }
}

// ---------------- fp16x3 MFMA FC2 via DMA: both operands pre-split ---------
// [512,4096] x [4096,4096]^T, split-K=4, 128x128 tile, K_STEP=64.
__global__ __launch_bounds__(256, 2) void fc2_dma(
    const _Float16* __restrict__ ah_g, const _Float16* __restrict__ al_g,
    const _Float16* __restrict__ bh_g, const _Float16* __restrict__ bl_g,
    float* __restrict__ part, int kslice)
{
    constexpr int K = 4096, N = 4096;
    const int t    = threadIdx.x;
    const int lane = t & 63;
    const int wid  = t >> 6;
    const int l15  = lane & 15;
    const int quad = lane >> 4;
    const int wm   = (wid >> 1) << 6;
    const int wn   = (wid & 1) << 6;

    const int drow  = lane >> 3;
    const int pslot = lane & 7;
    const int slog  = pslot ^ drow;

    __shared__ __align__(16) _Float16 Ah[128 * 64];
    __shared__ __align__(16) _Float16 Al[128 * 64];
    __shared__ __align__(16) _Float16 Bh[128 * 64];
    __shared__ __align__(16) _Float16 Bl[128 * 64];

    const int n0 = blockIdx.x << 7;
    const int m0 = blockIdx.y << 7;
    const int kbeg = blockIdx.z * kslice;

    float4v acc1[16], acc2[16];
#pragma unroll
    for (int i = 0; i < 16; ++i) {
        acc1[i] = (float4v)(0.f);
        acc2[i] = (float4v)(0.f);
    }

    for (int kb = 0; kb < kslice; kb += 64) {
#pragma unroll
        for (int ii = 0; ii < 4; ++ii) {
            const int iA = (wid << 2) + ii;
            const size_t ga = (size_t)(m0 + (iA << 3) + drow) * K + kbeg + kb + (slog << 3);
            gload_lds16(ah_g + ga, &Ah[(size_t)iA << 9]);
            gload_lds16(al_g + ga, &Al[(size_t)iA << 9]);
            const size_t gb = (size_t)(n0 + (iA << 3) + drow) * K + kbeg + kb + (slog << 3);
            gload_lds16(bh_g + gb, &Bh[(size_t)iA << 9]);
            gload_lds16(bl_g + gb, &Bl[(size_t)iA << 9]);
        }
        __syncthreads();
#pragma unroll
        for (int kh2 = 0; kh2 < 2; ++kh2) {
            half8 a_h[4], a_l[4], b_h[4], b_l[4];
#pragma unroll
            for (int i = 0; i < 4; ++i) {
                const int ra  = wm + (i << 4) + l15;
                const int sa  = ((kh2 << 2) + quad) ^ (ra & 7);
                const int oa  = (ra << 6) + (sa << 3);
                a_h[i] = *(const half8*)&Ah[oa];
                a_l[i] = *(const half8*)&Al[oa];
                const int rb  = wn + (i << 4) + l15;
                const int sb  = ((kh2 << 2) + quad) ^ (rb & 7);
                const int ob  = (rb << 6) + (sb << 3);
                b_h[i] = *(const half8*)&Bh[ob];
                b_l[i] = *(const half8*)&Bl[ob];
            }
#pragma unroll
            for (int mi = 0; mi < 4; ++mi)
#pragma unroll
                for (int ni = 0; ni < 4; ++ni) {
                    const int ix = mi * 4 + ni;
                    acc1[ix] = __builtin_amdgcn_mfma_f32_16x16x32_f16(a_h[mi], b_h[ni], acc1[ix], 0, 0, 0);
                    acc2[ix] = __builtin_amdgcn_mfma_f32_16x16x32_f16(a_h[mi], b_l[ni], acc2[ix], 0, 0, 0);
                    acc2[ix] = __builtin_amdgcn_mfma_f32_16x16x32_f16(a_l[mi], b_h[ni], acc2[ix], 0, 0, 0);
                }
        }
        __syncthreads();
    }
    float* po = part + (size_t)blockIdx.z * (512 * 4096);
#pragma unroll
    for (int mi = 0; mi < 4; ++mi)
#pragma unroll
        for (int ni = 0; ni < 4; ++ni) {
            const int ix = mi * 4 + ni;
            const int gn = n0 + wn + (ni << 4) + l15;
#pragma unroll
            for (int r = 0; r < 4; ++r) {
                const int m = m0 + wm + (mi << 4) + (quad << 2) + r;
                po[(size_t)m * N + gn] = acc1[ix][r] + acc2[ix][r] * (1.0f / 2048.0f);
            }
        }
}

// ---------------- split-K reduce for FC2 (+bias+relu) ----------------------
__global__ __launch_bounds__(256) void fc2_reduce_kernel(
    const float* __restrict__ part, const float* __restrict__ bias,
    float* __restrict__ out)
{
    int idx = blockIdx.x * 256 + threadIdx.x;   // < 512*4096
    if (idx >= 512 * 4096) return;
    const size_t MN = (size_t)512 * 4096;
    float s = 0.f;
#pragma unroll
    for (int zz = 0; zz < 4; ++zz) s += part[zz * MN + idx];
    s += bias[idx & 4095];
    out[idx] = fmaxf(s, 0.f);
}

// ---------------- FC1 fp32 GEMM (K=160, small) -----------------------------
template<bool RELU>
__global__ __launch_bounds__(256) void fc_gemm(
    const float* __restrict__ A, const float* __restrict__ Bw,
    const float* __restrict__ bias, float* __restrict__ out,
    int K, int N)
{
    const int t  = threadIdx.x;
    const int j0 = blockIdx.x << 6;
    const int m0 = blockIdx.y << 7;

    __shared__ __align__(16) float As[16 * 132];
    __shared__ __align__(16) float Bs[16 * 64];

    float acc[8][4];
#pragma unroll
    for (int a = 0; a < 8; ++a)
#pragma unroll
        for (int b = 0; b < 4; ++b) acc[a][b] = 0.f;

    const int a_m  = t >> 2;
    const int a_k  = (t & 3) << 2;
    const int b_j  = t & 63;
    const int b_k0 = (t >> 6) << 2;
    const int ms = (t >> 4) << 3;
    const int js = (t & 15) << 2;

    for (int kb0 = 0; kb0 < K; kb0 += 16) {
#pragma unroll
        for (int r = 0; r < 2; ++r) {
            int m = m0 + a_m + (r << 6);
            float4 av = *(const float4*)(A + (size_t)m * K + kb0 + a_k);
            As[(a_k + 0) * 132 + a_m + (r << 6)] = av.x;
            As[(a_k + 1) * 132 + a_m + (r << 6)] = av.y;
            As[(a_k + 2) * 132 + a_m + (r << 6)] = av.z;
            As[(a_k + 3) * 132 + a_m + (r << 6)] = av.w;
        }
        {
            float4 bv = *(const float4*)(Bw + (size_t)(j0 + b_j) * K + kb0 + b_k0);
            Bs[(b_k0 + 0) * 64 + b_j] = bv.x;
            Bs[(b_k0 + 1) * 64 + b_j] = bv.y;
            Bs[(b_k0 + 2) * 64 + b_j] = bv.z;
            Bs[(b_k0 + 3) * 64 + b_j] = bv.w;
        }
        __syncthreads();
#pragma unroll
        for (int kk = 0; kk < 16; ++kk) {
            float4 A0 = *(const float4*)&As[kk * 132 + ms];
            float4 A1 = *(const float4*)&As[kk * 132 + ms + 4];
            float4 B0 = *(const float4*)&Bs[(kk << 6) + js];
            float av[8] = {A0.x, A0.y, A0.z, A0.w, A1.x, A1.y, A1.z, A1.w};
            float bv[4] = {B0.x, B0.y, B0.z, B0.w};
#pragma unroll
            for (int mm = 0; mm < 8; ++mm)
#pragma unroll
                for (int jj = 0; jj < 4; ++jj)
                    acc[mm][jj] = fmaf(av[mm], bv[jj], acc[mm][jj]);
        }
        __syncthreads();
    }
    float4 b4 = *(const float4*)(bias + j0 + js);
#pragma unroll
    for (int mm = 0; mm < 8; ++mm) {
        float4 o;
        o.x = acc[mm][0] + b4.x;
        o.y = acc[mm][1] + b4.y;
        o.z = acc[mm][2] + b4.z;
        o.w = acc[mm][3] + b4.w;
        if (RELU) {
            o.x = fmaxf(o.x, 0.f); o.y = fmaxf(o.y, 0.f);
            o.z = fmaxf(o.z, 0.f); o.w = fmaxf(o.w, 0.f);
        }
        *(float4*)(out + (size_t)(m0 + ms + mm) * N + j0 + js) = o;
    }
}

// ---------------- squash of primary caps -----------------------------------
__global__ __launch_bounds__(256) void squash_kernel(
    const float* __restrict__ p, float* __restrict__ u)
{
    int cap = blockIdx.x * 256 + threadIdx.x;   // < 512*512
    if (cap >= 512 * 512) return;
    const float4* pi = (const float4*)(p + (size_t)cap * 8);
    float4 a = pi[0], b = pi[1];
    float sq = a.x * a.x + a.y * a.y + a.z * a.z + a.w * a.w
             + b.x * b.x + b.y * b.y + b.z * b.z + b.w * b.w;
    float f  = sq / (1.f + sq);
    float rs = sqrtf(sq + 1e-8f);
    float4 o0, o1;
    o0.x = (f * a.x) / rs; o0.y = (f * a.y) / rs;
    o0.z = (f * a.z) / rs; o0.w = (f * a.w) / rs;
    o1.x = (f * b.x) / rs; o1.y = (f * b.y) / rs;
    o1.z = (f * b.z) / rs; o1.w = (f * b.w) / rs;
    float4* po = (float4*)(u + (size_t)cap * 8);
    po[0] = o0; po[1] = o1;
}

// ---------------- x_hat precompute: xh[o][v][b][i] (half-batch) ------------
__global__ __launch_bounds__(256) void xhat_kernel(
    const float* __restrict__ u,   // [256][512][8] (half-batch base)
    const float* __restrict__ Wr,  // [10][512][16][8]
    float* __restrict__ xh)        // [10][16][256][512]
{
    const int t  = threadIdx.x;
    const int o  = blockIdx.y;
    const int i0 = blockIdx.x << 5;
    const int ii = t & 31;
    const int bs = t >> 5;                 // 0..7

    __shared__ __align__(16) float wsh[32 * 132];

    const float* wsrc = Wr + ((size_t)o * 512 + i0) * 128;
    for (int idx = t; idx < 1024; idx += 256) {
        float4 wv = *(const float4*)(wsrc + idx * 4);
        int r = (idx * 4) >> 7;
        int c = (idx * 4) & 127;
        *(float4*)&wsh[r * 132 + c] = wv;
    }
    __syncthreads();

    const int i = i0 + ii;
    const float* wrow = &wsh[ii * 132];

#pragma unroll
    for (int cch = 0; cch < 4; ++cch) {
        float uu[8][8];
#pragma unroll
        for (int l = 0; l < 8; ++l) {
            int b = bs + (cch << 6) + (l << 3);
            float4 u0 = *(const float4*)(u + (size_t)b * 4096 + i * 8);
            float4 u1 = *(const float4*)(u + (size_t)b * 4096 + i * 8 + 4);
            uu[l][0] = u0.x; uu[l][1] = u0.y; uu[l][2] = u0.z; uu[l][3] = u0.w;
            uu[l][4] = u1.x; uu[l][5] = u1.y; uu[l][6] = u1.z; uu[l][7] = u1.w;
        }
#pragma unroll
        for (int v = 0; v < 16; ++v) {
            float4 w0 = *(const float4*)&wrow[v << 3];
            float4 w1 = *(const float4*)&wrow[(v << 3) + 4];
            float acc[8];
#pragma unroll
            for (int l = 0; l < 8; ++l) {
                acc[l] = uu[l][0] * w0.x + uu[l][1] * w0.y + uu[l][2] * w0.z + uu[l][3] * w0.w
                       + uu[l][4] * w1.x + uu[l][5] * w1.y + uu[l][6] * w1.z + uu[l][7] * w1.w;
            }
#pragma unroll
            for (int l = 0; l < 8; ++l) {
                int b = bs + (cch << 6) + (l << 3);
                xh[(((size_t)(o << 4) + v) * 256 + b) * 512 + i] = acc[l];
            }
        }
    }
}

// ---------------- routing from precomputed x_hat (shuffle-free) ------------
__global__ __launch_bounds__(256) void routing2_kernel(
    const float* __restrict__ xh,  // [10][16][256][512]
    float* __restrict__ vout)      // [256][160] (half base)
{
    const int b = blockIdx.x;
    const int t = threadIdx.x;

    __shared__ __align__(16) float b_s[5120];
    __shared__ __align__(16) float c_s[5120];
    __shared__ float s_s[160];
    __shared__ float v_s[160];

    for (int idx = t; idx < 5120; idx += 256) b_s[idx] = 0.f;
    __syncthreads();

    const int o_t = t >> 4;
    const float* xrow = xh + ((size_t)t * 256 + b) * 512;

    for (int it = 0; it < 3; ++it) {
        for (int i = t; i < 512; i += 256) {
            float bv[10], mx = -3.4e38f;
#pragma unroll
            for (int o = 0; o < 10; ++o) { bv[o] = b_s[(o << 9) + i]; mx = fmaxf(mx, bv[o]); }
            float sum = 0.f;
#pragma unroll
            for (int o = 0; o < 10; ++o) { bv[o] = expf(bv[o] - mx); sum += bv[o]; }
            float inv = 1.f / sum;
#pragma unroll
            for (int o = 0; o < 10; ++o) c_s[(o << 9) + i] = bv[o] * inv;
        }
        __syncthreads();
        if (t < 160) {
            const float* cp = c_s + (o_t << 9);
            float4 a0 = {0.f, 0.f, 0.f, 0.f};
            float4 a1 = {0.f, 0.f, 0.f, 0.f};
            for (int i = 0; i < 512; i += 8) {
                float4 x0 = *(const float4*)(xrow + i);
                float4 x1 = *(const float4*)(xrow + i + 4);
                float4 c0 = *(const float4*)(cp + i);
                float4 c1 = *(const float4*)(cp + i + 4);
                a0.x = fmaf(x0.x, c0.x, a0.x); a0.y = fmaf(x0.y, c0.y, a0.y);
                a0.z = fmaf(x0.z, c0.z, a0.z); a0.w = fmaf(x0.w, c0.w, a0.w);
                a1.x = fmaf(x1.x, c1.x, a1.x); a1.y = fmaf(x1.y, c1.y, a1.y);
                a1.z = fmaf(x1.z, c1.z, a1.z); a1.w = fmaf(x1.w, c1.w, a1.w);
            }
            s_s[t] = (a0.x + a0.y) + (a0.z + a0.w) + (a1.x + a1.y) + (a1.z + a1.w);
        }
        __syncthreads();
        if (t < 10) {
            float tv[16], sq = 0.f;
#pragma unroll
            for (int v = 0; v < 16; ++v) { tv[v] = s_s[(t << 4) + v]; sq = fmaf(tv[v], tv[v], sq); }
            float f  = sq / (1.f + sq);
            float rs = sqrtf(sq + 1e-8f);
#pragma unroll
            for (int v = 0; v < 16; ++v) v_s[(t << 4) + v] = (f * tv[v]) / rs;
        }
        __syncthreads();
        if (it < 2) {
            for (int p = t; p < 5120; p += 256) {
                int o = p >> 9;
                int i = p & 511;
                const float* xp = xh + ((size_t)(o << 4) * 256 + b) * 512 + i;
                float acc = b_s[p];
#pragma unroll
                for (int v = 0; v < 16; ++v)
                    acc = fmaf(v_s[(o << 4) + v], xp[(size_t)v * (256 * 512)], acc);
                b_s[p] = acc;
            }
            __syncthreads();
        }
    }

    for (int idx = t; idx < 160; idx += 256) vout[(size_t)b * 160 + idx] = v_s[idx];
}

// ---------------- FC3: [512,4096] x [10,4096]^T + b -> [512,10] ------------
__global__ __launch_bounds__(256) void fc3_kernel(
    const float* __restrict__ f, const float* __restrict__ w,
    const float* __restrict__ bias, float* __restrict__ out)
{
    const int n = blockIdx.x;
    const int t = threadIdx.x;
    const int lane = t & 63, wv = t >> 6;
    const float* fr = f + (size_t)n * 4096;
    float p[10];
#pragma unroll
    for (int j = 0; j < 10; ++j) p[j] = 0.f;
    for (int k = t; k < 4096; k += 256) {
        float x = fr[k];
#pragma unroll
        for (int j = 0; j < 10; ++j) p[j] = fmaf(x, w[j * 4096 + k], p[j]);
    }
    __shared__ float red[4 * 10];
#pragma unroll
    for (int j = 0; j < 10; ++j) {
        float x = p[j];
        for (int off = 32; off > 0; off >>= 1) x += __shfl_xor(x, off);
        p[j] = x;
    }
    if (lane == 0) {
#pragma unroll
        for (int j = 0; j < 10; ++j) red[wv * 10 + j] = p[j];
    }
    __syncthreads();
    if (t < 10)
        out[(size_t)n * 10 + t] = red[t] + red[10 + t] + red[20 + t] + red[30 + t] + bias[t];
}

// ===========================================================================
extern "C" void kernel_launch(void* const* d_in, const int* in_sizes, int n_in,
                              void* d_out, int out_size, void* d_ws, size_t ws_size,
                              hipStream_t stream)
{
    const float* x   = (const float*)d_in[0];
    const float* w1  = (const float*)d_in[1];
    const float* b1  = (const float*)d_in[2];
    const float* w2  = (const float*)d_in[3];
    const float* b2  = (const float*)d_in[4];
    const float* w3  = (const float*)d_in[5];
    const float* b3  = (const float*)d_in[6];
    const float* w4  = (const float*)d_in[7];
    const float* b4  = (const float*)d_in[8];
    const float* w5  = (const float*)d_in[9];
    const float* b5  = (const float*)d_in[10];
    const float* wp  = (const float*)d_in[11];
    const float* bp  = (const float*)d_in[12];
    const float* Wr  = (const float*)d_in[13];
    const float* fw1 = (const float*)d_in[14];
    const float* fb1 = (const float*)d_in[15];
    const float* fw2 = (const float*)d_in[16];
    const float* fb2 = (const float*)d_in[17];
    const float* fw3 = (const float*)d_in[18];
    const float* fb3 = (const float*)d_in[19];
    float* outp = (float*)d_out;

    char* w = (char*)d_ws;
    // ---- static region: K-padded split weights + zero page -----------------
    _Float16* w2h  = (_Float16*)(w + 115605504);   //   458,752
    _Float16* w2l  = (_Float16*)(w + 116064256);   //   458,752 -> 116,523,008
    _Float16* w3h  = (_Float16*)(w + 116523008);   // 1,769,472
    _Float16* w3l  = (_Float16*)(w + 118292480);   //        -> 120,061,952
    _Float16* w4h  = (_Float16*)(w + 120061952);   // 2,654,208
    _Float16* w4l  = (_Float16*)(w + 122716160);   //        -> 125,370,368
    _Float16* w5h  = (_Float16*)(w + 125370368);   // 1,769,472
    _Float16* w5l  = (_Float16*)(w + 127139840);   //        -> 128,909,312
    _Float16* wph  = (_Float16*)(w + 128909312);   //   524,288
    _Float16* wpl  = (_Float16*)(w + 129433600);   //        -> 129,957,888
    float*    zp   = (float*)(w + 129957888);      //       256 -> 129,958,144

    // ---- dynamic region timeline (r12 FIX: a2 planes are 25,690,112 B each)
    _Float16* p1h  = (_Float16*)(w + 0);           // 19,267,584
    _Float16* p1l  = (_Float16*)(w + 19267584);    // ends 38,535,168
    _Float16* a2h  = (_Float16*)(w + 38535168);    // 25,690,112 (half batch)
    _Float16* a2l  = (_Float16*)(w + 64225280);    // ends 89,915,392 (= p2h)
    _Float16* p2h  = (_Float16*)(w + 89915392);    // 12,845,056
    _Float16* p2l  = (_Float16*)(w + 102760448);   // ends 115,605,504
    _Float16* a3h  = (_Float16*)(w + 0);           // 19,267,584
    _Float16* a3l  = (_Float16*)(w + 19267584);    // ends 38,535,168
    _Float16* a4h  = (_Float16*)(w + 38535168);    // 19,267,584
    _Float16* a4l  = (_Float16*)(w + 57802752);    // ends 77,070,336
    _Float16* a5h  = (_Float16*)(w + 0);           // 12,845,056
    _Float16* a5l  = (_Float16*)(w + 12845056);    // ends 25,690,112
    _Float16* p3h  = (_Float16*)(w + 25690112);    // 6,553,600
    _Float16* p3l  = (_Float16*)(w + 32243712);    // ends 38,797,312 (a4 dead by then)
    float*    pc   = (float*)(w + 0);              //  8,388,608
    float*    u    = (float*)(w + 8388608);        //  8,388,608, ends 16,777,216
    float*    vcap = (float*)(w + 16777216);       //    327,680, ends 17,104,896
    float*    xh   = (float*)(w + 17104896);       // 83,886,080, ends 100,990,976

    // ---- FC phase layout (xh dead after routing; audited disjoint) --------
    float*    f1   = (float*)(w + 17104896);       //  8,388,608, ends 25,493,504
    _Float16* fw2h = (_Float16*)(w + 33882112);    // 33,554,432, ends 67,436,544
    _Float16* fw2l = (_Float16*)(w + 67436544);    // 33,554,432, ends 100,990,976
    _Float16* f1h  = (_Float16*)(w + 100990976);   //  4,194,304
    _Float16* f1l  = (_Float16*)(w + 105185280);   //  ends 109,379,584
    float*    part = (float*)(w + 0);              // 33,554,432 (4 slices)
    float*    f2   = (float*)(w + 33882112);       //  8,388,608 (fw2h dead at reduce)

    // ---- zero page + pre-split weights (reordered (kh,kw,ic), K-padded) ---
    zero_kernel<<<dim3(1), dim3(64), 0, stream>>>(zp);
    wsplit_pad_kernel<<<dim3(896),  dim3(256), 0, stream>>>(w2, w2h, w2l,  96, 9,  864,  896,  229376);
    wsplit_pad_kernel<<<dim3(3456), dim3(256), 0, stream>>>(w3, w3h, w3l, 256, 9, 2304, 2304,  884736);
    wsplit_pad_kernel<<<dim3(5184), dim3(256), 0, stream>>>(w4, w4h, w4l, 384, 9, 3456, 3456, 1327104);
    wsplit_pad_kernel<<<dim3(3456), dim3(256), 0, stream>>>(w5, w5h, w5l, 384, 9, 3456, 3456,  884736);
    wsplit_pad_kernel<<<dim3(1024), dim3(256), 0, stream>>>(wp, wph, wpl, 256, 4, 1024, 1024,  262144);

    // conv1 + relu + pool1 : x -> p1 split NHWC [512,14,14,96]
    conv1_pool_nhwc<<<dim3(37632), dim3(256), 0, stream>>>(x, w1, b1, p1h, p1l);

    // conv2 + relu (split f16 NHWC out), two batch halves, each pooled
    conv_dma<96, 14, 14, 3, 1, 256, 128, 392, 1><<<dim3(784), dim3(256), 0, stream>>>(
        p1h, p1l, w2h, w2l, b2, zp, nullptr, a2h, a2l, 0);
    maxpool_resplit<256, 256, 14, 14, 7, 7, 3, 2, 1><<<dim3(12544), dim3(256), 0, stream>>>(
        a2h, a2l, p2h, p2l);
    conv_dma<96, 14, 14, 3, 1, 256, 128, 392, 1><<<dim3(784), dim3(256), 0, stream>>>(
        p1h, p1l, w2h, w2l, b2, zp, nullptr, a2h, a2l, 50176);
    maxpool_resplit<256, 256, 14, 14, 7, 7, 3, 2, 1><<<dim3(12544), dim3(256), 0, stream>>>(
        a2h, a2l, p2h + (size_t)3211264, p2l + (size_t)3211264);

    // conv3 + relu : p2 -> a3 split NHWC [512,7,7,384]
    conv_dma<256, 7, 7, 3, 1, 384, 128, 196, 1><<<dim3(588), dim3(256), 0, stream>>>(
        p2h, p2l, w3h, w3l, b3, zp, nullptr, a3h, a3l, 0);
    // conv4 + relu : a3 -> a4 split NHWC [512,7,7,384]
    conv_dma<384, 7, 7, 3, 1, 384, 128, 196, 1><<<dim3(588), dim3(256), 0, stream>>>(
        a3h, a3l, w4h, w4l, b4, zp, nullptr, a4h, a4l, 0);
    // conv5 + relu : a4 -> a5 split NHWC [512,7,7,256]
    conv_dma<384, 7, 7, 3, 1, 256, 128, 196, 1><<<dim3(392), dim3(256), 0, stream>>>(
        a4h, a4l, w5h, w5l, b5, zp, nullptr, a5h, a5l, 0);
    // pool3 : a5 -> p3 split NHWC [512,5,5,256]
    maxpool_resplit<512, 256, 7, 7, 5, 5, 3, 1, 0><<<dim3(12800), dim3(256), 0, stream>>>(
        a5h, a5l, p3h, p3l);
    // primary caps conv (k2,s1,p0, no relu) : p3 -> pc fp32 NCHW [512,256,4,4]
    conv_dma<256, 5, 5, 2, 0, 256, 64, 128, 2><<<dim3(256), dim3(256), 0, stream>>>(
        p3h, p3l, wph, wpl, bp, zp, pc, nullptr, nullptr, 0);
    // squash : pc -> u [512,512,8]
    squash_kernel<<<dim3(1024), dim3(256), 0, stream>>>(pc, u);

    // dynamic routing via precomputed x_hat, two half-batches
    for (int h = 0; h < 2; ++h) {
        const float* uh = u + (size_t)h * 256 * 4096;
        float* vh = vcap + (size_t)h * 256 * 160;
        xhat_kernel<<<dim3(16, 10), dim3(256), 0, stream>>>(uh, Wr, xh);
        routing2_kernel<<<dim3(256), dim3(256), 0, stream>>>(xh, vh);
    }

    // one-time fw2 split to f16 hi/lo (xh region dead now)
    split_kernel<<<dim3(65536), dim3(256), 0, stream>>>(fw2, fw2h, fw2l, 16777216);

    // FC1 + relu (fp32, K=160) : vcap -> f1 [512,4096]
    fc_gemm<true><<<dim3(64, 4), dim3(256), 0, stream>>>(vcap, fw1, fb1, f1, 160, 4096);
    // split f1
    split_kernel<<<dim3(8192), dim3(256), 0, stream>>>(f1, f1h, f1l, 2097152);
    // FC2 DMA split-K=4 : f1s x fw2s -> part [4,512,4096]
    fc2_dma<<<dim3(32, 4, 4), dim3(256), 0, stream>>>(f1h, f1l, fw2h, fw2l, part, 1024);
    // reduce + bias + relu : part -> f2 [512,4096]
    fc2_reduce_kernel<<<dim3(8192), dim3(256), 0, stream>>>(part, fb2, f2);
    // FC3 : f2 -> out [512,10]
    fc3_kernel<<<dim3(512), dim3(256), 0, stream>>>(f2, fw3, fb3, outp);
}

// Round 7
// 1384.609 us; speedup vs baseline: 1.2915x; 1.0430x over previous
//
#include <hip/hip_runtime.h>
#include <math.h>

// ===========================================================================
// AlexCapsNet forward. Big convs + FC2 via fp16x3-split MFMA (16x16x32_f16).
// a = ah + al/2048 (al stored pre-scaled by 2048 to stay in f16 normal range).
// C = sum ah*bh  +  (sum ah*bl + al*bh) / 2048      (al*bl dropped, ~2^-22)
//
// Round 13 = r9 base (proven 1403us; r12's swizzle+pool-resplit reverted:
// measured neutral-to-negative) + SPLIT-K=2 for conv3/conv4.
//  Diagnosis: conv4 Occupancy 14% / max 25% = 56% == 588 blocks over 512
//  resident slots -> 2 dispatch rounds, round 2 only 76 blocks (grid tail).
//  Active-time MfmaUtil ~66% (near the LDS-BW ceiling of this layout) -- the
//  engine is fine, the tail is the loss.
//  Fix: conv3/conv4 run as 2 K-slices (grid z), each slice writes split-f16
//  PARTIAL pairs (no bias/relu) to a 77.1MB scratch; a vectorized combine
//  kernel sums partials + bias + relu -> split activation pair. G=1176 ->
//  3 rounds -> 77% util. No atomics, deterministic.
//  WS audit (byte-level, r11 lesson): cpart [0,77.07M); a3/a4 pair at
//  [77.07M,115.6M) (p2 / a3 dead when written); conv5->a5 fp32 [0,25.7M);
//  p3 [25.7M,38.8M); pc [0,8.4M). All pairs disjoint at use time.
// ===========================================================================

#define BATCH 512

typedef _Float16 half8  __attribute__((ext_vector_type(8)));
typedef _Float16 half4v __attribute__((ext_vector_type(4)));
typedef float   float4v __attribute__((ext_vector_type(4)));

// ---------------- global->LDS 16B DMA helper -------------------------------
__device__ __forceinline__ void gload_lds16(const void* g, void* l)
{
    __builtin_amdgcn_global_load_lds(
        (const __attribute__((address_space(1))) unsigned int*)g,
        (__attribute__((address_space(3))) unsigned int*)l,
        16, 0, 0);
}

// ---------------- zero page ------------------------------------------------
__global__ __launch_bounds__(64) void zero_kernel(float* __restrict__ z)
{
    z[threadIdx.x] = 0.f;
}

// ---------------- fp32 -> (hi f16, lo f16*2048) split (linear) -------------
__global__ __launch_bounds__(256) void split_kernel(
    const float* __restrict__ src, _Float16* __restrict__ hi,
    _Float16* __restrict__ lo, int n)
{
    int idx = blockIdx.x * 256 + threadIdx.x;
    if (idx >= n) return;
    float v = src[idx];
    _Float16 h = (_Float16)v;
    hi[idx] = h;
    lo[idx] = (_Float16)((v - (float)h) * 2048.0f);
}

// -------- weight reorder [oc][ic][kh][kw] -> [oc][(kh,kw,ic) padded] + split
__global__ __launch_bounds__(256) void wsplit_pad_kernel(
    const float* __restrict__ src, _Float16* __restrict__ hi,
    _Float16* __restrict__ lo, int IC, int KK, int K, int KP, int total)
{
    int idx = blockIdx.x * 256 + threadIdx.x;   // idx = oc*KP + k
    if (idx >= total) return;
    int k  = idx % KP;
    int oc = idx / KP;
    float v = 0.f;
    if (k < K) {
        int khkw = k / IC;
        int ic   = k - khkw * IC;
        v = src[((size_t)(oc * IC + ic)) * KK + khkw];
    }
    _Float16 h = (_Float16)v;
    hi[idx] = h;
    lo[idx] = (_Float16)((v - (float)h) * 2048.0f);
}

// ---------------- conv1(1->96,3x3,p1) + relu + maxpool(3,2,1) fused --------
// Output: NHWC split f16 hi/lo [512][14][14][96]
__global__ __launch_bounds__(256) void conv1_pool_nhwc(
    const float* __restrict__ x, const float* __restrict__ w1,
    const float* __restrict__ b1, _Float16* __restrict__ oh_,
    _Float16* __restrict__ ol_)
{
    int idx = blockIdx.x * 256 + threadIdx.x;   // = ((n*14+oh)*14+ow)*96+oc
    if (idx >= 512 * 14 * 14 * 96) return;
    int oc = idx % 96; int t1 = idx / 96;
    int ow = t1 % 14;  int t2 = t1 / 14;
    int oh = t2 % 14;  int n  = t2 / 14;
    const float* xi = x + n * 784;
    float w[9];
#pragma unroll
    for (int i = 0; i < 9; ++i) w[i] = w1[oc * 9 + i];
    float bias = b1[oc];
    float best = -3.4e38f;
#pragma unroll
    for (int dy = 0; dy < 3; ++dy) {
        int ph = oh * 2 - 1 + dy;
        if ((unsigned)ph >= 28u) continue;
#pragma unroll
        for (int dx = 0; dx < 3; ++dx) {
            int pw = ow * 2 - 1 + dx;
            if ((unsigned)pw >= 28u) continue;
            float s = bias;
#pragma unroll
            for (int ky = 0; ky < 3; ++ky) {
                int iy = ph - 1 + ky;
                if ((unsigned)iy >= 28u) continue;
#pragma unroll
                for (int kx = 0; kx < 3; ++kx) {
                    int ix = pw - 1 + kx;
                    if ((unsigned)ix >= 28u) continue;
                    s = fmaf(w[ky * 3 + kx], xi[iy * 28 + ix], s);
                }
            }
            s = fmaxf(s, 0.f);
            best = fmaxf(best, s);
        }
    }
    _Float16 h = (_Float16)best;
    oh_[idx] = h;
    ol_[idx] = (_Float16)((best - (float)h) * 2048.0f);
}

// ---------------- NHWC maxpool (fp32 in) -> split f16 hi/lo out ------------
template<int NB, int C, int H, int W, int OH, int OW, int KS, int STR, int PADP>
__global__ __launch_bounds__(256) void maxpool_nhwc_split(
    const float* __restrict__ in, _Float16* __restrict__ po,
    _Float16* __restrict__ pl)
{
    constexpr int TOTAL = NB * OH * OW * C;
    int idx = blockIdx.x * 256 + threadIdx.x;   // = ((n*OH+oh)*OW+ow)*C+c
    if (idx >= TOTAL) return;
    int c  = idx % C;  int t1 = idx / C;
    int ow = t1 % OW;  int t2 = t1 / OW;
    int oh = t2 % OH;  int n  = t2 / OH;
    const float* ip = in + (size_t)n * (H * W * C) + c;
    float best = -3.4e38f;
#pragma unroll
    for (int dy = 0; dy < KS; ++dy) {
        int ih = oh * STR - PADP + dy;
        if ((unsigned)ih >= (unsigned)H) continue;
#pragma unroll
        for (int dx = 0; dx < KS; ++dx) {
            int iw = ow * STR - PADP + dx;
            if ((unsigned)iw >= (unsigned)W) continue;
            best = fmaxf(best, ip[(size_t)(ih * W + iw) * C]);
        }
    }
    _Float16 h = (_Float16)best;
    po[idx] = h;
    pl[idx] = (_Float16)((best - (float)h) * 2048.0f);
}

// ---------------- fp16x3 MFMA implicit-GEMM conv, DMA + swizzled LDS -------
// M = OC (tile 128), N = batch*OHW (tile NT), K = KH*KH*IC (step 64).
// Grid (n-blocks, m-blocks, ZS): ZS K-slices (split-K), each KP/ZS long.
// LDS rows = 64 halfs (128 B, 8 slots of 16 B), phys_slot = slot ^ (row&7).
// DMA source pre-inverse-swizzled per lane. OOB taps DMA from zero page.
// OUTMODE: 0 = fp32 NHWC + relu, 1 = split f16 NHWC + relu, 2 = fp32 NCHW,
//          4 = split f16 PARTIAL pair (no bias/relu), plane = blockIdx.z.
template<int IC, int H, int W, int KH, int PAD, int OC, int NT, int ZS, int OUTMODE>
__global__ __launch_bounds__(256, 2) void conv_dma(
    const _Float16* __restrict__ inh, const _Float16* __restrict__ inl,
    const _Float16* __restrict__ whi, const _Float16* __restrict__ wlo,
    const float* __restrict__ bias, const float* __restrict__ zpage,
    float* __restrict__ outf, _Float16* __restrict__ outh,
    _Float16* __restrict__ outl, int n_base)
{
    constexpr int OH  = H + 2 * PAD - KH + 1;
    constexpr int OW  = W + 2 * PAD - KH + 1;
    constexpr int OHW = OH * OW;
    constexpr int K   = IC * KH * KH;
    constexpr int KP  = (K + 63) & ~63;
    constexpr int KSL = KP / ZS;             // K-slice length
    static_assert(KSL % 64 == 0, "slice must be K-step aligned");
    constexpr int NFRAG = NT / 32;           // per-wave N fragments
    constexpr int NBI   = NT / 32;           // B DMA instrs per wave
    constexpr bool UNIF = (IC % 64 == 0) && (KP == K);
    constexpr int HWIC = H * W * IC;

    const int t    = threadIdx.x;
    const int lane = t & 63;
    const int wid  = t >> 6;
    const int l15  = lane & 15;
    const int quad = lane >> 4;
    const int wm   = (wid >> 1) << 6;        // 0 / 64
    const int wn   = (wid & 1) * (NT / 2);

    const int drow  = lane >> 3;             // row within 8-row DMA group
    const int pslot = lane & 7;              // physical slot this lane fills
    const int slog  = pslot ^ drow;          // logical slot to fetch

    __shared__ __align__(16) _Float16 Ah[128 * 64];
    __shared__ __align__(16) _Float16 Al[128 * 64];
    __shared__ __align__(16) _Float16 Bh[NT * 64];
    __shared__ __align__(16) _Float16 Bl[NT * 64];

    const int n0 = blockIdx.x * NT;
    const int m0 = blockIdx.y << 7;
    const int kbeg = blockIdx.z * KSL;

    float4v acc1[4 * NFRAG], acc2[4 * NFRAG];
#pragma unroll
    for (int i = 0; i < 4 * NFRAG; ++i) {
        acc1[i] = (float4v)(0.f);
        acc2[i] = (float4v)(0.f);
    }

    // per-lane B geometry (per DMA instr)
    int bU[NBI], ohU[NBI], owU[NBI];
#pragma unroll
    for (int ii = 0; ii < NBI; ++ii) {
        int nl = ((wid * NBI + ii) << 3) + drow;
        int gn = n_base + n0 + nl;
        int b  = gn / OHW;
        int p  = gn - b * OHW;
        int o  = p / OW;
        bU[ii] = b; ohU[ii] = o; owU[ii] = p - o * OW;
    }

    int khkw = kbeg / IC;                    // mid-slice start handled
    int icb  = kbeg - khkw * IC;
    for (int kb = kbeg; kb < kbeg + KSL; kb += 64) {
        // ---- A DMA (weights, linear rows of stride KP) ----
#pragma unroll
        for (int ii = 0; ii < 4; ++ii) {
            const int iA = (wid << 2) + ii;
            const size_t go = (size_t)(m0 + (iA << 3) + drow) * KP + kb + (slog << 3);
            gload_lds16(whi + go, &Ah[(size_t)iA << 9]);
            gload_lds16(wlo + go, &Al[(size_t)iA << 9]);
        }
        // ---- B DMA (im2col gather via per-lane source) ----
        if constexpr (UNIF) {
            const int kh = khkw / KH;
            const int kw = khkw - kh * KH;
#pragma unroll
            for (int ii = 0; ii < NBI; ++ii) {
                const int iB = wid * NBI + ii;
                const int ih = ohU[ii] + kh - PAD;
                const int iw = owU[ii] + kw - PAD;
                const bool ok = ((unsigned)ih < (unsigned)H) && ((unsigned)iw < (unsigned)W);
                const size_t off = (size_t)bU[ii] * HWIC + (ih * W + iw) * IC + icb + (slog << 3);
                const _Float16* sh = ok ? inh + off : (const _Float16*)zpage;
                const _Float16* sl = ok ? inl + off : (const _Float16*)zpage;
                gload_lds16(sh, &Bh[(size_t)iB << 9]);
                gload_lds16(sl, &Bl[(size_t)iB << 9]);
            }
            icb += 64;
            if (icb == IC) { icb = 0; ++khkw; }
        } else {
            const int kpl = kb + (slog << 3);        // per-lane k
            const int kkl = kpl / IC;
            const int icl = kpl - kkl * IC;
            const int khl = kkl / KH;
            const int kwl = kkl - khl * KH;
#pragma unroll
            for (int ii = 0; ii < NBI; ++ii) {
                const int iB = wid * NBI + ii;
                const int ih = ohU[ii] + khl - PAD;
                const int iw = owU[ii] + kwl - PAD;
                const bool ok = (kpl < K) && ((unsigned)ih < (unsigned)H) &&
                                ((unsigned)iw < (unsigned)W);
                const size_t off = (size_t)bU[ii] * HWIC + (ih * W + iw) * IC + icl;
                const _Float16* sh = ok ? inh + off : (const _Float16*)zpage;
                const _Float16* sl = ok ? inl + off : (const _Float16*)zpage;
                gload_lds16(sh, &Bh[(size_t)iB << 9]);
                gload_lds16(sl, &Bl[(size_t)iB << 9]);
            }
        }
        __syncthreads();                             // drains vmcnt -> tile ready
        // ---- compute: two k-halves of 32 ----
#pragma unroll
        for (int kh2 = 0; kh2 < 2; ++kh2) {
            half8 a_h[4], a_l[4], b_h[NFRAG], b_l[NFRAG];
#pragma unroll
            for (int i = 0; i < 4; ++i) {
                const int r  = wm + (i << 4) + l15;
                const int sl = ((kh2 << 2) + quad) ^ (r & 7);
                const int off = (r << 6) + (sl << 3);
                a_h[i] = *(const half8*)&Ah[off];
                a_l[i] = *(const half8*)&Al[off];
            }
#pragma unroll
            for (int i = 0; i < NFRAG; ++i) {
                const int r  = wn + (i << 4) + l15;
                const int sl = ((kh2 << 2) + quad) ^ (r & 7);
                const int off = (r << 6) + (sl << 3);
                b_h[i] = *(const half8*)&Bh[off];
                b_l[i] = *(const half8*)&Bl[off];
            }
#pragma unroll
            for (int mi = 0; mi < 4; ++mi)
#pragma unroll
                for (int ni = 0; ni < NFRAG; ++ni) {
                    const int ix = mi * NFRAG + ni;
                    acc1[ix] = __builtin_amdgcn_mfma_f32_16x16x32_f16(a_h[mi], b_h[ni], acc1[ix], 0, 0, 0);
                    acc2[ix] = __builtin_amdgcn_mfma_f32_16x16x32_f16(a_h[mi], b_l[ni], acc2[ix], 0, 0, 0);
                    acc2[ix] = __builtin_amdgcn_mfma_f32_16x16x32_f16(a_l[mi], b_h[ni], acc2[ix], 0, 0, 0);
                }
        }
        __syncthreads();                             // reads done before next DMA
    }
    // ---- epilogue ----
    const size_t zoff = (size_t)blockIdx.z * ((size_t)gridDim.x * NT * OC * 2);
#pragma unroll
    for (int mi = 0; mi < 4; ++mi)
#pragma unroll
        for (int ni = 0; ni < NFRAG; ++ni) {
            const int ix = mi * NFRAG + ni;
            const int gn = n_base + n0 + wn + (ni << 4) + l15;
            const int ln = gn - n_base;
            const int mb = m0 + wm + (mi << 4) + (quad << 2);
            float4v bv;
            if constexpr (OUTMODE != 4) bv = *(const float4v*)(bias + mb);
            else                        bv = (float4v)(0.f);
            float vv[4];
#pragma unroll
            for (int r = 0; r < 4; ++r) {
                float v = acc1[ix][r] + acc2[ix][r] * (1.0f / 2048.0f) + bv[r];
                if (OUTMODE != 2 && OUTMODE != 4) v = fmaxf(v, 0.f);
                vv[r] = v;
            }
            if (OUTMODE == 0) {
                float4v o = {vv[0], vv[1], vv[2], vv[3]};
                *(float4v*)(outf + (size_t)ln * OC + mb) = o;
            } else if (OUTMODE == 1 || OUTMODE == 4) {
                half4v hh, ll;
#pragma unroll
                for (int r = 0; r < 4; ++r) {
                    _Float16 h = (_Float16)vv[r];
                    hh[r] = h;
                    ll[r] = (_Float16)((vv[r] - (float)h) * 2048.0f);
                }
                *(half4v*)(outh + zoff + (size_t)ln * OC + mb) = hh;
                *(half4v*)(outl + zoff + (size_t)ln * OC + mb) = ll;
            } else {
                int b = gn / OHW;
                int p = gn - b * OHW;
#pragma unroll
                for (int r = 0; r < 4; ++r)
                    outf[((size_t)b * OC + mb + r) * OHW + p] = vv[r];
            }
        }
}

// ---------------- split-K combine: 2 partial pairs + bias + relu -> pair ---
// total8 = N*OC/8; zoff (elements) = distance between z-plane bases.
__global__ __launch_bounds__(256) void conv_combine2(
    const _Float16* __restrict__ p0h, const _Float16* __restrict__ p0l,
    const float* __restrict__ bias, _Float16* __restrict__ oh,
    _Float16* __restrict__ ol, int total8, int OC, size_t zoff)
{
    int t8 = blockIdx.x * 256 + threadIdx.x;
    if (t8 >= total8) return;
    size_t base = (size_t)t8 * 8;
    half8 ah = *(const half8*)(p0h + base);
    half8 al = *(const half8*)(p0l + base);
    half8 bh = *(const half8*)(p0h + zoff + base);
    half8 bl = *(const half8*)(p0l + zoff + base);
    int oc0 = (int)(base % (size_t)OC);
    half8 hh, ll;
#pragma unroll
    for (int j = 0; j < 8; ++j) {
        float v = (float)ah[j] + (float)al[j] * (1.0f / 2048.0f)
                + (float)bh[j] + (float)bl[j] * (1.0f / 2048.0f)
                + bias[oc0 + j];
        v = fmaxf(v, 0.f);
        _Float16 h = (_Float16)v;
        hh[j] = h;
        ll[j] = (_Float16)((v - (float)h) * 2048.0f);
    }
    *(half8*)(oh + base) = hh;
    *(half8*)(ol + base) = ll;
}

// ---------------- fp16x3 MFMA FC2 via DMA: both operands pre-split ---------
// [512,4096] x [4096,4096]^T, split-K=4, 128x128 tile, K_STEP=64.
__global__ __launch_bounds__(256, 2) void fc2_dma(
    const _Float16* __restrict__ ah_g, const _Float16* __restrict__ al_g,
    const _Float16* __restrict__ bh_g, const _Float16* __restrict__ bl_g,
    float* __restrict__ part, int kslice)
{
    constexpr int K = 4096, N = 4096;
    const int t    = threadIdx.x;
    const int lane = t & 63;
    const int wid  = t >> 6;
    const int l15  = lane & 15;
    const int quad = lane >> 4;
    const int wm   = (wid >> 1) << 6;
    const int wn   = (wid & 1) << 6;

    const int drow  = lane >> 3;
    const int pslot = lane & 7;
    const int slog  = pslot ^ drow;

    __shared__ __align__(16) _Float16 Ah[128 * 64];
    __shared__ __align__(16) _Float16 Al[128 * 64];
    __shared__ __align__(16) _Float16 Bh[128 * 64];
    __shared__ __align__(16) _Float16 Bl[128 * 64];

    const int n0 = blockIdx.x << 7;
    const int m0 = blockIdx.y << 7;
    const int kbeg = blockIdx.z * kslice;

    float4v acc1[16], acc2[16];
#pragma unroll
    for (int i = 0; i < 16; ++i) {
        acc1[i] = (float4v)(0.f);
        acc2[i] = (float4v)(0.f);
    }

    for (int kb = 0; kb < kslice; kb += 64) {
#pragma unroll
        for (int ii = 0; ii < 4; ++ii) {
            const int iA = (wid << 2) + ii;
            const size_t ga = (size_t)(m0 + (iA << 3) + drow) * K + kbeg + kb + (slog << 3);
            gload_lds16(ah_g + ga, &Ah[(size_t)iA << 9]);
            gload_lds16(al_g + ga, &Al[(size_t)iA << 9]);
            const size_t gb = (size_t)(n0 + (iA << 3) + drow) * K + kbeg + kb + (slog << 3);
            gload_lds16(bh_g + gb, &Bh[(size_t)iA << 9]);
            gload_lds16(bl_g + gb, &Bl[(size_t)iA << 9]);
        }
        __syncthreads();
#pragma unroll
        for (int kh2 = 0; kh2 < 2; ++kh2) {
            half8 a_h[4], a_l[4], b_h[4], b_l[4];
#pragma unroll
            for (int i = 0; i < 4; ++i) {
                const int ra  = wm + (i << 4) + l15;
                const int sa  = ((kh2 << 2) + quad) ^ (ra & 7);
                const int oa  = (ra << 6) + (sa << 3);
                a_h[i] = *(const half8*)&Ah[oa];
                a_l[i] = *(const half8*)&Al[oa];
                const int rb  = wn + (i << 4) + l15;
                const int sb  = ((kh2 << 2) + quad) ^ (rb & 7);
                const int ob  = (rb << 6) + (sb << 3);
                b_h[i] = *(const half8*)&Bh[ob];
                b_l[i] = *(const half8*)&Bl[ob];
            }
#pragma unroll
            for (int mi = 0; mi < 4; ++mi)
#pragma unroll
                for (int ni = 0; ni < 4; ++ni) {
                    const int ix = mi * 4 + ni;
                    acc1[ix] = __builtin_amdgcn_mfma_f32_16x16x32_f16(a_h[mi], b_h[ni], acc1[ix], 0, 0, 0);
                    acc2[ix] = __builtin_amdgcn_mfma_f32_16x16x32_f16(a_h[mi], b_l[ni], acc2[ix], 0, 0, 0);
                    acc2[ix] = __builtin_amdgcn_mfma_f32_16x16x32_f16(a_l[mi], b_h[ni], acc2[ix], 0, 0, 0);
                }
        }
        __syncthreads();
    }
    float* po = part + (size_t)blockIdx.z * (512 * 4096);
#pragma unroll
    for (int mi = 0; mi < 4; ++mi)
#pragma unroll
        for (int ni = 0; ni < 4; ++ni) {
            const int ix = mi * 4 + ni;
            const int gn = n0 + wn + (ni << 4) + l15;
#pragma unroll
            for (int r = 0; r < 4; ++r) {
                const int m = m0 + wm + (mi << 4) + (quad << 2) + r;
                po[(size_t)m * N + gn] = acc1[ix][r] + acc2[ix][r] * (1.0f / 2048.0f);
            }
        }
}

// ---------------- split-K reduce for FC2 (+bias+relu) ----------------------
__global__ __launch_bounds__(256) void fc2_reduce_kernel(
    const float* __restrict__ part, const float* __restrict__ bias,
    float* __restrict__ out)
{
    int idx = blockIdx.x * 256 + threadIdx.x;   // < 512*4096
    if (idx >= 512 * 4096) return;
    const size_t MN = (size_t)512 * 4096;
    float s = 0.f;
#pragma unroll
    for (int zz = 0; zz < 4; ++zz) s += part[zz * MN + idx];
    s += bias[idx & 4095];
    out[idx] = fmaxf(s, 0.f);
}

// ---------------- FC1 fp32 GEMM (K=160, small) -----------------------------
template<bool RELU>
__global__ __launch_bounds__(256) void fc_gemm(
    const float* __restrict__ A, const float* __restrict__ Bw,
    const float* __restrict__ bias, float* __restrict__ out,
    int K, int N)
{
    const int t  = threadIdx.x;
    const int j0 = blockIdx.x << 6;
    const int m0 = blockIdx.y << 7;

    __shared__ __align__(16) float As[16 * 132];
    __shared__ __align__(16) float Bs[16 * 64];

    float acc[8][4];
#pragma unroll
    for (int a = 0; a < 8; ++a)
#pragma unroll
        for (int b = 0; b < 4; ++b) acc[a][b] = 0.f;

    const int a_m  = t >> 2;
    const int a_k  = (t & 3) << 2;
    const int b_j  = t & 63;
    const int b_k0 = (t >> 6) << 2;
    const int ms = (t >> 4) << 3;
    const int js = (t & 15) << 2;

    for (int kb0 = 0; kb0 < K; kb0 += 16) {
#pragma unroll
        for (int r = 0; r < 2; ++r) {
            int m = m0 + a_m + (r << 6);
            float4 av = *(const float4*)(A + (size_t)m * K + kb0 + a_k);
            As[(a_k + 0) * 132 + a_m + (r << 6)] = av.x;
            As[(a_k + 1) * 132 + a_m + (r << 6)] = av.y;
            As[(a_k + 2) * 132 + a_m + (r << 6)] = av.z;
            As[(a_k + 3) * 132 + a_m + (r << 6)] = av.w;
        }
        {
            float4 bv = *(const float4*)(Bw + (size_t)(j0 + b_j) * K + kb0 + b_k0);
            Bs[(b_k0 + 0) * 64 + b_j] = bv.x;
            Bs[(b_k0 + 1) * 64 + b_j] = bv.y;
            Bs[(b_k0 + 2) * 64 + b_j] = bv.z;
            Bs[(b_k0 + 3) * 64 + b_j] = bv.w;
        }
        __syncthreads();
#pragma unroll
        for (int kk = 0; kk < 16; ++kk) {
            float4 A0 = *(const float4*)&As[kk * 132 + ms];
            float4 A1 = *(const float4*)&As[kk * 132 + ms + 4];
            float4 B0 = *(const float4*)&Bs[(kk << 6) + js];
            float av[8] = {A0.x, A0.y, A0.z, A0.w, A1.x, A1.y, A1.z, A1.w};
            float bv[4] = {B0.x, B0.y, B0.z, B0.w};
#pragma unroll
            for (int mm = 0; mm < 8; ++mm)
#pragma unroll
                for (int jj = 0; jj < 4; ++jj)
                    acc[mm][jj] = fmaf(av[mm], bv[jj], acc[mm][jj]);
        }
        __syncthreads();
    }
    float4 b4 = *(const float4*)(bias + j0 + js);
#pragma unroll
    for (int mm = 0; mm < 8; ++mm) {
        float4 o;
        o.x = acc[mm][0] + b4.x;
        o.y = acc[mm][1] + b4.y;
        o.z = acc[mm][2] + b4.z;
        o.w = acc[mm][3] + b4.w;
        if (RELU) {
            o.x = fmaxf(o.x, 0.f); o.y = fmaxf(o.y, 0.f);
            o.z = fmaxf(o.z, 0.f); o.w = fmaxf(o.w, 0.f);
        }
        *(float4*)(out + (size_t)(m0 + ms + mm) * N + j0 + js) = o;
    }
}

// ---------------- squash of primary caps -----------------------------------
__global__ __launch_bounds__(256) void squash_kernel(
    const float* __restrict__ p, float* __restrict__ u)
{
    int cap = blockIdx.x * 256 + threadIdx.x;   // < 512*512
    if (cap >= 512 * 512) return;
    const float4* pi = (const float4*)(p + (size_t)cap * 8);
    float4 a = pi[0], b = pi[1];
    float sq = a.x * a.x + a.y * a.y + a.z * a.z + a.w * a.w
             + b.x * b.x + b.y * b.y + b.z * b.z + b.w * b.w;
    float f  = sq / (1.f + sq);
    float rs = sqrtf(sq + 1e-8f);
    float4 o0, o1;
    o0.x = (f * a.x) / rs; o0.y = (f * a.y) / rs;
    o0.z = (f * a.z) / rs; o0.w = (f * a.w) / rs;
    o1.x = (f * b.x) / rs; o1.y = (f * b.y) / rs;
    o1.z = (f * b.z) / rs; o1.w = (f * b.w) / rs;
    float4* po = (float4*)(u + (size_t)cap * 8);
    po[0] = o0; po[1] = o1;
}

// ---------------- x_hat precompute: xh[o][v][b][i] (half-batch) ------------
__global__ __launch_bounds__(256) void xhat_kernel(
    const float* __restrict__ u,   // [256][512][8] (half-batch base)
    const float* __restrict__ Wr,  // [10][512][16][8]
    float* __restrict__ xh)        // [10][16][256][512]
{
    const int t  = threadIdx.x;
    const int o  = blockIdx.y;
    const int i0 = blockIdx.x << 5;
    const int ii = t & 31;
    const int bs = t >> 5;                 // 0..7

    __shared__ __align__(16) float wsh[32 * 132];

    const float* wsrc = Wr + ((size_t)o * 512 + i0) * 128;
    for (int idx = t; idx < 1024; idx += 256) {
        float4 wv = *(const float4*)(wsrc + idx * 4);
        int r = (idx * 4) >> 7;
        int c = (idx * 4) & 127;
        *(float4*)&wsh[r * 132 + c] = wv;
    }
    __syncthreads();

    const int i = i0 + ii;
    const float* wrow = &wsh[ii * 132];

#pragma unroll
    for (int cch = 0; cch < 4; ++cch) {
        float uu[8][8];
#pragma unroll
        for (int l = 0; l < 8; ++l) {
            int b = bs + (cch << 6) + (l << 3);
            float4 u0 = *(const float4*)(u + (size_t)b * 4096 + i * 8);
            float4 u1 = *(const float4*)(u + (size_t)b * 4096 + i * 8 + 4);
            uu[l][0] = u0.x; uu[l][1] = u0.y; uu[l][2] = u0.z; uu[l][3] = u0.w;
            uu[l][4] = u1.x; uu[l][5] = u1.y; uu[l][6] = u1.z; uu[l][7] = u1.w;
        }
#pragma unroll
        for (int v = 0; v < 16; ++v) {
            float4 w0 = *(const float4*)&wrow[v << 3];
            float4 w1 = *(const float4*)&wrow[(v << 3) + 4];
            float acc[8];
#pragma unroll
            for (int l = 0; l < 8; ++l) {
                acc[l] = uu[l][0] * w0.x + uu[l][1] * w0.y + uu[l][2] * w0.z + uu[l][3] * w0.w
                       + uu[l][4] * w1.x + uu[l][5] * w1.y + uu[l][6] * w1.z + uu[l][7] * w1.w;
            }
#pragma unroll
            for (int l = 0; l < 8; ++l) {
                int b = bs + (cch << 6) + (l << 3);
                xh[(((size_t)(o << 4) + v) * 256 + b) * 512 + i] = acc[l];
            }
        }
    }
}

// ---------------- routing from precomputed x_hat (shuffle-free) ------------
__global__ __launch_bounds__(256) void routing2_kernel(
    const float* __restrict__ xh,  // [10][16][256][512]
    float* __restrict__ vout)      // [256][160] (half base)
{
    const int b = blockIdx.x;
    const int t = threadIdx.x;

    __shared__ __align__(16) float b_s[5120];
    __shared__ __align__(16) float c_s[5120];
    __shared__ float s_s[160];
    __shared__ float v_s[160];

    for (int idx = t; idx < 5120; idx += 256) b_s[idx] = 0.f;
    __syncthreads();

    const int o_t = t >> 4;
    const float* xrow = xh + ((size_t)t * 256 + b) * 512;

    for (int it = 0; it < 3; ++it) {
        for (int i = t; i < 512; i += 256) {
            float bv[10], mx = -3.4e38f;
#pragma unroll
            for (int o = 0; o < 10; ++o) { bv[o] = b_s[(o << 9) + i]; mx = fmaxf(mx, bv[o]); }
            float sum = 0.f;
#pragma unroll
            for (int o = 0; o < 10; ++o) { bv[o] = expf(bv[o] - mx); sum += bv[o]; }
            float inv = 1.f / sum;
#pragma unroll
            for (int o = 0; o < 10; ++o) c_s[(o << 9) + i] = bv[o] * inv;
        }
        __syncthreads();
        if (t < 160) {
            const float* cp = c_s + (o_t << 9);
            float4 a0 = {0.f, 0.f, 0.f, 0.f};
            float4 a1 = {0.f, 0.f, 0.f, 0.f};
            for (int i = 0; i < 512; i += 8) {
                float4 x0 = *(const float4*)(xrow + i);
                float4 x1 = *(const float4*)(xrow + i + 4);
                float4 c0 = *(const float4*)(cp + i);
                float4 c1 = *(const float4*)(cp + i + 4);
                a0.x = fmaf(x0.x, c0.x, a0.x); a0.y = fmaf(x0.y, c0.y, a0.y);
                a0.z = fmaf(x0.z, c0.z, a0.z); a0.w = fmaf(x0.w, c0.w, a0.w);
                a1.x = fmaf(x1.x, c1.x, a1.x); a1.y = fmaf(x1.y, c1.y, a1.y);
                a1.z = fmaf(x1.z, c1.z, a1.z); a1.w = fmaf(x1.w, c1.w, a1.w);
            }
            s_s[t] = (a0.x + a0.y) + (a0.z + a0.w) + (a1.x + a1.y) + (a1.z + a1.w);
        }
        __syncthreads();
        if (t < 10) {
            float tv[16], sq = 0.f;
#pragma unroll
            for (int v = 0; v < 16; ++v) { tv[v] = s_s[(t << 4) + v]; sq = fmaf(tv[v], tv[v], sq); }
            float f  = sq / (1.f + sq);
            float rs = sqrtf(sq + 1e-8f);
#pragma unroll
            for (int v = 0; v < 16; ++v) v_s[(t << 4) + v] = (f * tv[v]) / rs;
        }
        __syncthreads();
        if (it < 2) {
            for (int p = t; p < 5120; p += 256) {
                int o = p >> 9;
                int i = p & 511;
                const float* xp = xh + ((size_t)(o << 4) * 256 + b) * 512 + i;
                float acc = b_s[p];
#pragma unroll
                for (int v = 0; v < 16; ++v)
                    acc = fmaf(v_s[(o << 4) + v], xp[(size_t)v * (256 * 512)], acc);
                b_s[p] = acc;
            }
            __syncthreads();
        }
    }

    for (int idx = t; idx < 160; idx += 256) vout[(size_t)b * 160 + idx] = v_s[idx];
}

// ---------------- FC3: [512,4096] x [10,4096]^T + b -> [512,10] ------------
__global__ __launch_bounds__(256) void fc3_kernel(
    const float* __restrict__ f, const float* __restrict__ w,
    const float* __restrict__ bias, float* __restrict__ out)
{
    const int n = blockIdx.x;
    const int t = threadIdx.x;
    const int lane = t & 63, wv = t >> 6;
    const float* fr = f + (size_t)n * 4096;
    float p[10];
#pragma unroll
    for (int j = 0; j < 10; ++j) p[j] = 0.f;
    for (int k = t; k < 4096; k += 256) {
        float x = fr[k];
#pragma unroll
        for (int j = 0; j < 10; ++j) p[j] = fmaf(x, w[j * 4096 + k], p[j]);
    }
    __shared__ float red[4 * 10];
#pragma unroll
    for (int j = 0; j < 10; ++j) {
        float x = p[j];
        for (int off = 32; off > 0; off >>= 1) x += __shfl_xor(x, off);
        p[j] = x;
    }
    if (lane == 0) {
#pragma unroll
        for (int j = 0; j < 10; ++j) red[wv * 10 + j] = p[j];
    }
    __syncthreads();
    if (t < 10)
        out[(size_t)n * 10 + t] = red[t] + red[10 + t] + red[20 + t] + red[30 + t] + bias[t];
}

// ===========================================================================
extern "C" void kernel_launch(void* const* d_in, const int* in_sizes, int n_in,
                              void* d_out, int out_size, void* d_ws, size_t ws_size,
                              hipStream_t stream)
{
    const float* x   = (const float*)d_in[0];
    const float* w1  = (const float*)d_in[1];
    const float* b1  = (const float*)d_in[2];
    const float* w2  = (const float*)d_in[3];
    const float* b2  = (const float*)d_in[4];
    const float* w3  = (const float*)d_in[5];
    const float* b3  = (const float*)d_in[6];
    const float* w4  = (const float*)d_in[7];
    const float* b4  = (const float*)d_in[8];
    const float* w5  = (const float*)d_in[9];
    const float* b5  = (const float*)d_in[10];
    const float* wp  = (const float*)d_in[11];
    const float* bp  = (const float*)d_in[12];
    const float* Wr  = (const float*)d_in[13];
    const float* fw1 = (const float*)d_in[14];
    const float* fb1 = (const float*)d_in[15];
    const float* fw2 = (const float*)d_in[16];
    const float* fb2 = (const float*)d_in[17];
    const float* fw3 = (const float*)d_in[18];
    const float* fb3 = (const float*)d_in[19];
    float* outp = (float*)d_out;

    char* w = (char*)d_ws;
    // ---- static region: K-padded split weights + zero page -----------------
    _Float16* w2h  = (_Float16*)(w + 115605504);   //   458,752
    _Float16* w2l  = (_Float16*)(w + 116064256);   //   458,752 -> 116,523,008
    _Float16* w3h  = (_Float16*)(w + 116523008);   // 1,769,472
    _Float16* w3l  = (_Float16*)(w + 118292480);   //        -> 120,061,952
    _Float16* w4h  = (_Float16*)(w + 120061952);   // 2,654,208
    _Float16* w4l  = (_Float16*)(w + 122716160);   //        -> 125,370,368
    _Float16* w5h  = (_Float16*)(w + 125370368);   // 1,769,472
    _Float16* w5l  = (_Float16*)(w + 127139840);   //        -> 128,909,312
    _Float16* wph  = (_Float16*)(w + 128909312);   //   524,288
    _Float16* wpl  = (_Float16*)(w + 129433600);   //        -> 129,957,888
    float*    zp   = (float*)(w + 129957888);      //       256 -> 129,958,144

    // ---- conv2 phase (r9 layout) -------------------------------------------
    _Float16* p1h  = (_Float16*)(w + 0);           // 19,267,584
    _Float16* p1l  = (_Float16*)(w + 19267584);    // ends 38,535,168
    float*    a2   = (float*)(w + 38535168);       // 51,380,224 (half batch), ends 89,915,392
    _Float16* p2h  = (_Float16*)(w + 89915392);    // 12,845,056
    _Float16* p2l  = (_Float16*)(w + 102760448);   // ends 115,605,504

    // ---- split-K partial region for conv3/conv4 (each plane 19,267,584 B) --
    // layout: z0h@0, z0l@19,267,584, z1h@38,535,168, z1l@57,802,752 -> 77,070,336
    _Float16* cp0h = (_Float16*)(w + 0);
    _Float16* cp0l = (_Float16*)(w + 19267584);
    // a3 / a4 pair lives above the partials (p2 / a3 dead when written)
    _Float16* a3h  = (_Float16*)(w + 77070336);    // 19,267,584
    _Float16* a3l  = (_Float16*)(w + 96337920);    // ends 115,605,504
    _Float16* a4h  = (_Float16*)(w + 77070336);    // same region, a3 dead at write
    _Float16* a4l  = (_Float16*)(w + 96337920);
    float*    a5   = (float*)(w + 0);              // 25,690,112 (partials dead)
    _Float16* p3h  = (_Float16*)(w + 25690112);    // 6,553,600
    _Float16* p3l  = (_Float16*)(w + 32243712);    // ends 38,797,312 (a4 @77M+ safe)
    float*    pc   = (float*)(w + 0);              //  8,388,608 (a5 dead)
    float*    u    = (float*)(w + 8388608);        //  8,388,608, ends 16,777,216
    float*    vcap = (float*)(w + 16777216);       //    327,680, ends 17,104,896
    float*    xh   = (float*)(w + 17104896);       // 83,886,080, ends 100,990,976

    // ---- FC phase layout (xh dead after routing; audited disjoint) --------
    float*    f1   = (float*)(w + 17104896);       //  8,388,608, ends 25,493,504
    _Float16* fw2h = (_Float16*)(w + 33882112);    // 33,554,432, ends 67,436,544
    _Float16* fw2l = (_Float16*)(w + 67436544);    // 33,554,432, ends 100,990,976
    _Float16* f1h  = (_Float16*)(w + 100990976);   //  4,194,304
    _Float16* f1l  = (_Float16*)(w + 105185280);   //  ends 109,379,584
    float*    part = (float*)(w + 0);              // 33,554,432 (4 slices)
    float*    f2   = (float*)(w + 33882112);       //  8,388,608 (fw2h dead at reduce)

    // ---- zero page + pre-split weights (reordered (kh,kw,ic), K-padded) ---
    zero_kernel<<<dim3(1), dim3(64), 0, stream>>>(zp);
    wsplit_pad_kernel<<<dim3(896),  dim3(256), 0, stream>>>(w2, w2h, w2l,  96, 9,  864,  896,  229376);
    wsplit_pad_kernel<<<dim3(3456), dim3(256), 0, stream>>>(w3, w3h, w3l, 256, 9, 2304, 2304,  884736);
    wsplit_pad_kernel<<<dim3(5184), dim3(256), 0, stream>>>(w4, w4h, w4l, 384, 9, 3456, 3456, 1327104);
    wsplit_pad_kernel<<<dim3(3456), dim3(256), 0, stream>>>(w5, w5h, w5l, 384, 9, 3456, 3456,  884736);
    wsplit_pad_kernel<<<dim3(1024), dim3(256), 0, stream>>>(wp, wph, wpl, 256, 4, 1024, 1024,  262144);

    // conv1 + relu + pool1 : x -> p1 split NHWC [512,14,14,96]
    conv1_pool_nhwc<<<dim3(37632), dim3(256), 0, stream>>>(x, w1, b1, p1h, p1l);

    // conv2 + relu (fp32 NHWC out), two batch halves, each followed by pool2
    conv_dma<96, 14, 14, 3, 1, 256, 128, 1, 0><<<dim3(392, 2), dim3(256), 0, stream>>>(
        p1h, p1l, w2h, w2l, b2, zp, a2, nullptr, nullptr, 0);
    maxpool_nhwc_split<256, 256, 14, 14, 7, 7, 3, 2, 1><<<dim3(12544), dim3(256), 0, stream>>>(
        a2, p2h, p2l);
    conv_dma<96, 14, 14, 3, 1, 256, 128, 1, 0><<<dim3(392, 2), dim3(256), 0, stream>>>(
        p1h, p1l, w2h, w2l, b2, zp, a2, nullptr, nullptr, 50176);
    maxpool_nhwc_split<256, 256, 14, 14, 7, 7, 3, 2, 1><<<dim3(12544), dim3(256), 0, stream>>>(
        a2, p2h + (size_t)3211264, p2l + (size_t)3211264);

    // conv3 split-K=2 : p2 -> partials -> combine -> a3 split NHWC [512,7,7,384]
    conv_dma<256, 7, 7, 3, 1, 384, 128, 2, 4><<<dim3(196, 3, 2), dim3(256), 0, stream>>>(
        p2h, p2l, w3h, w3l, b3, zp, nullptr, cp0h, cp0l, 0);
    conv_combine2<<<dim3(4704), dim3(256), 0, stream>>>(
        cp0h, cp0l, b3, a3h, a3l, 1204224, 384, (size_t)19267584);
    // conv4 split-K=2 : a3 -> partials -> combine -> a4 split NHWC [512,7,7,384]
    conv_dma<384, 7, 7, 3, 1, 384, 128, 2, 4><<<dim3(196, 3, 2), dim3(256), 0, stream>>>(
        a3h, a3l, w4h, w4l, b4, zp, nullptr, cp0h, cp0l, 0);
    conv_combine2<<<dim3(4704), dim3(256), 0, stream>>>(
        cp0h, cp0l, b4, a4h, a4l, 1204224, 384, (size_t)19267584);
    // conv5 + relu : a4 -> a5 fp32 NHWC [512,7,7,256]
    conv_dma<384, 7, 7, 3, 1, 256, 128, 1, 0><<<dim3(196, 2), dim3(256), 0, stream>>>(
        a4h, a4l, w5h, w5l, b5, zp, a5, nullptr, nullptr, 0);
    // pool3 : a5 -> p3 split NHWC [512,5,5,256]
    maxpool_nhwc_split<512, 256, 7, 7, 5, 5, 3, 1, 0><<<dim3(12800), dim3(256), 0, stream>>>(
        a5, p3h, p3l);
    // primary caps conv (k2,s1,p0, no relu) : p3 -> pc fp32 NCHW [512,256,4,4]
    conv_dma<256, 5, 5, 2, 0, 256, 64, 1, 2><<<dim3(128, 2), dim3(256), 0, stream>>>(
        p3h, p3l, wph, wpl, bp, zp, pc, nullptr, nullptr, 0);
    // squash : pc -> u [512,512,8]
    squash_kernel<<<dim3(1024), dim3(256), 0, stream>>>(pc, u);

    // dynamic routing via precomputed x_hat, two half-batches
    for (int h = 0; h < 2; ++h) {
        const float* uh = u + (size_t)h * 256 * 4096;
        float* vh = vcap + (size_t)h * 256 * 160;
        xhat_kernel<<<dim3(16, 10), dim3(256), 0, stream>>>(uh, Wr, xh);
        routing2_kernel<<<dim3(256), dim3(256), 0, stream>>>(xh, vh);
    }

    // one-time fw2 split to f16 hi/lo (xh region dead now)
    split_kernel<<<dim3(65536), dim3(256), 0, stream>>>(fw2, fw2h, fw2l, 16777216);

    // FC1 + relu (fp32, K=160) : vcap -> f1 [512,4096]
    fc_gemm<true><<<dim3(64, 4), dim3(256), 0, stream>>>(vcap, fw1, fb1, f1, 160, 4096);
    // split f1
    split_kernel<<<dim3(8192), dim3(256), 0, stream>>>(f1, f1h, f1l, 2097152);
    // FC2 DMA split-K=4 : f1s x fw2s -> part [4,512,4096]
    fc2_dma<<<dim3(32, 4, 4), dim3(256), 0, stream>>>(f1h, f1l, fw2h, fw2l, part, 1024);
    // reduce + bias + relu : part -> f2 [512,4096]
    fc2_reduce_kernel<<<dim3(8192), dim3(256), 0, stream>>>(part, fb2, f2);
    // FC3 : f2 -> out [512,10]
    fc3_kernel<<<dim3(512), dim3(256), 0, stream>>>(f2, fw3, fb3, outp);
}